// Round 3
// baseline (434.737 us; speedup 1.0000x reference)
//
#include <hip/hip_runtime.h>
#include <math.h>

#define NATOMS 2000
#define NNBR   30
#define NCONF  8
#define APC    250
#define NRAD   12
#define M3     20
#define H1N    64
#define H2N    32

__device__ __forceinline__ float sigmoidf(float v) {
    return 1.0f / (1.0f + __expf(-v));
}

// Per-atom shared buffers. Union overlays phase-disjoint data:
//   d3w  : P1 (3-body fwd partials)         dead after P2 start
//   gz2  : P3->P4 (layer2 grads)            dead after P4
//   rd   : P5..P7 (cross-chunk reductions)
struct AtomBuf {
    float u[NNBR][3];
    float fcb[NNBR];
    float h1[NNBR][65];      // z1 sigmoid fwd; overwritten with g_z1 in P4
    float gd3[NNBR][25];     // dE/d(d3[m]) per row
    union {
        float d3w[2][NNBR][21];
        float gz2[NNBR][33];
        struct { float red[4][NNBR][4]; float red2[4][NNBR][4]; } rd;
    } ov;
};

// 256 threads = 4 waves = 2 atoms x 2 waves.
// Within an atom: lane row = pair index (30 active), chunk c = wslot*2+half
// splits q-loop {8,8,7,7}, h-dim (16 each), k-dim (8 each), d-dim (8 each).
extern "C" __global__ void __launch_bounds__(256, 4)
fit_main(const float* __restrict__ x, const float* __restrict__ tx,
         const int* __restrict__ uj,
         const float* __restrict__ W1, const float* __restrict__ b1,
         const float* __restrict__ W2, const float* __restrict__ b2,
         const float* __restrict__ W3, const float* __restrict__ b3,
         float* __restrict__ gx, float* __restrict__ e_atom)
{
    __shared__ AtomBuf ab[2];

    const int tid    = threadIdx.x;
    const int sub    = tid >> 7;            // atom slot in block
    const int wslot  = (tid >> 6) & 1;      // wave within atom
    const int lane   = tid & 63;
    const int half   = lane >> 5;
    const int row    = lane & 31;
    const int c      = wslot * 2 + half;    // chunk 0..3
    const int atom   = blockIdx.x * 2 + sub;
    const bool act   = (row < NNBR);
    AtomBuf& B = ab[sub];

    const float k1  = 0.6283185307179586f;   // pi/5
    const float sq  = 0.6324555320336759f;   // sqrt(2/5)
    const float eta = 45.125f;               // 1/(2*dmu^2), dmu=2/19

    const int qn    = (c >= 2) ? 7 : 8;
    const int q0    = c * 8 - ((c == 3) ? 1 : 0);
    const int hbase = c * 16;
    const int kbase = c * 8;
    const int dbase = c * 8;

    // ---------------- P0: pair geometry (redundant per chunk) ----------------
    float r = 1.f, rinv = 1.f, u0 = 0.f, u1 = 0.f, u2 = 0.f;
    float fc = 0.f, ca = 1.f, sa = 0.f;
    int j = 0;
    if (act) {
        int p = atom * NNBR + row;
        j = uj[p];
        float d0 = x[atom * 3 + 0] - x[j * 3 + 0] - tx[p * 3 + 0];
        float d1 = x[atom * 3 + 1] - x[j * 3 + 1] - tx[p * 3 + 1];
        float d2 = x[atom * 3 + 2] - x[j * 3 + 2] - tx[p * 3 + 2];
        r = sqrtf(d0 * d0 + d1 * d1 + d2 * d2);
        rinv = 1.0f / r;
        u0 = d0 * rinv; u1 = d1 * rinv; u2 = d2 * rinv;
        __sincosf(k1 * r, &sa, &ca);
        fc = 0.5f * (ca + 1.0f);
        if (c == 0) {
            B.u[row][0] = u0; B.u[row][1] = u1; B.u[row][2] = u2;
            B.fcb[row] = fc;
        }
    }
    __syncthreads();

    // ---------------- P1: 3-body forward (q-chunked) ----------------
    float d3p[M3];
#pragma unroll
    for (int m = 0; m < M3; m++) d3p[m] = 0.f;
    if (act) {
        for (int qq = 0; qq < qn; qq++) {
            int q = q0 + qq;
            float vq0 = B.u[q][0], vq1 = B.u[q][1], vq2 = B.u[q][2];
            float fq = (q == row) ? 0.f : B.fcb[q];
            float cs = u0 * vq0 + u1 * vq1 + u2 * vq2;
#pragma unroll
            for (int m = 0; m < M3; m++) {
                float mu = -1.0f + (float)m * (2.0f / 19.0f);
                float t = cs - mu;
                d3p[m] = fmaf(fq, __expf(-eta * t * t), d3p[m]);
            }
        }
    }
#pragma unroll
    for (int m = 0; m < M3; m++) d3p[m] += __shfl_xor(d3p[m], 32);
    if (act && half == 0) {
#pragma unroll
        for (int m = 0; m < M3; m++) B.ov.d3w[wslot][row][m] = d3p[m];
    }
    __syncthreads();

    float d3f[M3];
    if (act) {
#pragma unroll
        for (int m = 0; m < M3; m++)
            d3f[m] = B.ov.d3w[0][row][m] + B.ov.d3w[1][row][m];
    }

    // ---------------- P2: layer1 forward (h-chunk of 16) ----------------
    float h1v[16];
    if (act) {
#pragma unroll
        for (int t = 0; t < 4; t++) {
            float4 v = *(const float4*)&b1[hbase + 4 * t];
            h1v[4 * t + 0] = v.x; h1v[4 * t + 1] = v.y;
            h1v[4 * t + 2] = v.z; h1v[4 * t + 3] = v.w;
        }
        float sprev = 0.f, scur = sa;
        float coef = fc * sq * rinv;
        for (int d = 0; d < NRAD; d++) {
            float rb = coef * scur;
#pragma unroll
            for (int t = 0; t < 4; t++) {
                float4 w = *(const float4*)&W1[d * H1N + hbase + 4 * t];
                h1v[4 * t + 0] = fmaf(rb, w.x, h1v[4 * t + 0]);
                h1v[4 * t + 1] = fmaf(rb, w.y, h1v[4 * t + 1]);
                h1v[4 * t + 2] = fmaf(rb, w.z, h1v[4 * t + 2]);
                h1v[4 * t + 3] = fmaf(rb, w.w, h1v[4 * t + 3]);
            }
            float snext = 2.f * ca * scur - sprev; sprev = scur; scur = snext;
        }
#pragma unroll
        for (int m = 0; m < M3; m++) {
            float dv = d3f[m];
#pragma unroll
            for (int t = 0; t < 4; t++) {
                float4 w = *(const float4*)&W1[(NRAD + m) * H1N + hbase + 4 * t];
                h1v[4 * t + 0] = fmaf(dv, w.x, h1v[4 * t + 0]);
                h1v[4 * t + 1] = fmaf(dv, w.y, h1v[4 * t + 1]);
                h1v[4 * t + 2] = fmaf(dv, w.z, h1v[4 * t + 2]);
                h1v[4 * t + 3] = fmaf(dv, w.w, h1v[4 * t + 3]);
            }
        }
#pragma unroll
        for (int hh = 0; hh < 16; hh++) h1v[hh] = sigmoidf(h1v[hh]);
#pragma unroll
        for (int hh = 0; hh < 16; hh++) B.h1[row][hbase + hh] = h1v[hh];
    }
    __syncthreads();

    // ---------------- P3: layer2 forward (k-chunk of 8) ----------------
    float outp = 0.f;
    if (act) {
        float acc[8];
#pragma unroll
        for (int kk = 0; kk < 8; kk++) acc[kk] = b2[kbase + kk];
        for (int h = 0; h < H1N; h++) {
            float hv = B.h1[row][h];
            const float4* wp = (const float4*)&W2[h * H2N + kbase];
            float4 wa = wp[0], wb = wp[1];
            acc[0] = fmaf(hv, wa.x, acc[0]); acc[1] = fmaf(hv, wa.y, acc[1]);
            acc[2] = fmaf(hv, wa.z, acc[2]); acc[3] = fmaf(hv, wa.w, acc[3]);
            acc[4] = fmaf(hv, wb.x, acc[4]); acc[5] = fmaf(hv, wb.y, acc[5]);
            acc[6] = fmaf(hv, wb.z, acc[6]); acc[7] = fmaf(hv, wb.w, acc[7]);
        }
#pragma unroll
        for (int kk = 0; kk < 8; kk++) {
            float s = sigmoidf(acc[kk]);
            float w3 = W3[kbase + kk];
            outp = fmaf(s, w3, outp);
            B.ov.gz2[row][kbase + kk] = fc * w3 * s * (1.f - s);
        }
    }
    __syncthreads();

    // ---------------- P4: layer2 backward -> g_z1 (h-chunk) ----------------
    float gh1[16];
#pragma unroll
    for (int hh = 0; hh < 16; hh++) gh1[hh] = 0.f;
    if (act) {
#pragma unroll
        for (int kb = 0; kb < 2; kb++) {
            float g16[16];
#pragma unroll
            for (int t = 0; t < 16; t++) g16[t] = B.ov.gz2[row][kb * 16 + t];
#pragma unroll
            for (int hh = 0; hh < 16; hh++) {
                int h = hbase + hh;
                const float4* wp = (const float4*)&W2[h * H2N + kb * 16];
                float4 wa = wp[0], wb = wp[1], wc = wp[2], wd = wp[3];
                float a = gh1[hh];
                a = fmaf(g16[0],  wa.x, a); a = fmaf(g16[1],  wa.y, a);
                a = fmaf(g16[2],  wa.z, a); a = fmaf(g16[3],  wa.w, a);
                a = fmaf(g16[4],  wb.x, a); a = fmaf(g16[5],  wb.y, a);
                a = fmaf(g16[6],  wb.z, a); a = fmaf(g16[7],  wb.w, a);
                a = fmaf(g16[8],  wc.x, a); a = fmaf(g16[9],  wc.y, a);
                a = fmaf(g16[10], wc.z, a); a = fmaf(g16[11], wc.w, a);
                a = fmaf(g16[12], wd.x, a); a = fmaf(g16[13], wd.y, a);
                a = fmaf(g16[14], wd.w == wd.w ? wd.z : wd.z, a); // keep order
                a = fmaf(g16[15], wd.w, a);
                gh1[hh] = a;
            }
        }
#pragma unroll
        for (int hh = 0; hh < 16; hh++) {
            float hv = h1v[hh];
            gh1[hh] = gh1[hh] * hv * (1.f - hv);
        }
#pragma unroll
        for (int hh = 0; hh < 16; hh++) B.h1[row][hbase + hh] = gh1[hh];
    }
    __syncthreads();

    // ---------------- P5: layer1 backward (d-chunk of 8) ----------------
    if (act) {
        float gd[8];
#pragma unroll
        for (int dd = 0; dd < 8; dd++) gd[dd] = 0.f;
#pragma unroll
        for (int hb = 0; hb < 4; hb++) {
            float g16[16];
#pragma unroll
            for (int t = 0; t < 16; t++) g16[t] = B.h1[row][hb * 16 + t];
#pragma unroll
            for (int dd = 0; dd < 8; dd++) {
                int d = dbase + dd;
                const float4* wp = (const float4*)&W1[d * H1N + hb * 16];
                float4 wa = wp[0], wb = wp[1], wc = wp[2], wd = wp[3];
                float a = gd[dd];
                a = fmaf(g16[0],  wa.x, a); a = fmaf(g16[1],  wa.y, a);
                a = fmaf(g16[2],  wa.z, a); a = fmaf(g16[3],  wa.w, a);
                a = fmaf(g16[4],  wb.x, a); a = fmaf(g16[5],  wb.y, a);
                a = fmaf(g16[6],  wb.z, a); a = fmaf(g16[7],  wb.w, a);
                a = fmaf(g16[8],  wc.x, a); a = fmaf(g16[9],  wc.y, a);
                a = fmaf(g16[10], wc.z, a); a = fmaf(g16[11], wc.w, a);
                a = fmaf(g16[12], wd.x, a); a = fmaf(g16[13], wd.y, a);
                a = fmaf(g16[14], wd.z, a); a = fmaf(g16[15], wd.w, a);
                gd[dd] = a;
            }
        }
        // rbf-derivative part (chunks owning d<12) + gd3 publication (d>=12)
        float grp = 0.f, gfp = 0.f;
        float scur = 0.f, ccur = 1.f, sprev = 0.f, cprev = 1.f;
        if (dbase < NRAD) {
            __sincosf((float)(dbase + 1) * k1 * r, &scur, &ccur);
            sprev = scur * ca - ccur * sa;   // sin((n0-1)*a)
            cprev = ccur * ca + scur * sa;   // cos((n0-1)*a)
        }
#pragma unroll
        for (int dd = 0; dd < 8; dd++) {
            int d = dbase + dd;
            if (d < NRAD) {
                float n = (float)(d + 1);
                grp += gd[dd] * fc * sq * rinv * (n * k1 * ccur - scur * rinv);
                gfp += gd[dd] * sq * scur * rinv;
                float snext = 2.f * ca * scur - sprev; sprev = scur; scur = snext;
                float cnext = 2.f * ca * ccur - cprev; cprev = ccur; ccur = cnext;
            } else {
                B.gd3[row][d - NRAD] = gd[dd];
            }
        }
        B.ov.rd.red2[c][row][0] = grp;
        B.ov.rd.red2[c][row][1] = gfp;
        B.ov.rd.red2[c][row][2] = outp;
    }
    __syncthreads();

    // ---------------- P6: 3-body backward (q-chunked) ----------------
    if (act) {
        float A[M3];
#pragma unroll
        for (int m = 0; m < M3; m++) A[m] = B.gd3[row][m];
        float gu0 = 0.f, gu1 = 0.f, gu2 = 0.f, gfcp = 0.f;
        for (int qq = 0; qq < qn; qq++) {
            int q = q0 + qq;
            float vq0 = B.u[q][0], vq1 = B.u[q][1], vq2 = B.u[q][2];
            float fq = B.fcb[q];
            float cs = u0 * vq0 + u1 * vq1 + u2 * vq2;
            float sA0 = 0.f, sA1 = 0.f, sB0 = 0.f, sB1 = 0.f, sG0 = 0.f, sG1 = 0.f;
#pragma unroll
            for (int m = 0; m < M3; m += 2) {
                float mu0 = -1.0f + (float)m * (2.0f / 19.0f);
                float mu1 = -1.0f + (float)(m + 1) * (2.0f / 19.0f);
                float t0 = cs - mu0, t1 = cs - mu1;
                float e0 = __expf(-eta * t0 * t0);
                float e1 = __expf(-eta * t1 * t1);
                float de0 = -2.f * eta * t0 * e0;
                float de1 = -2.f * eta * t1 * e1;
                float B0 = B.gd3[q][m], B1 = B.gd3[q][m + 1];
                sA0 = fmaf(A[m], de0, sA0);     sA1 = fmaf(A[m + 1], de1, sA1);
                sB0 = fmaf(B0, de0, sB0);       sB1 = fmaf(B1, de1, sB1);
                sG0 = fmaf(B0, e0, sG0);        sG1 = fmaf(B1, e1, sG1);
            }
            if (q != row) {
                gfcp += sG0 + sG1;
                float gcos = fq * (sA0 + sA1) + fc * (sB0 + sB1);
                gu0 = fmaf(gcos, vq0, gu0);
                gu1 = fmaf(gcos, vq1, gu1);
                gu2 = fmaf(gcos, vq2, gu2);
            }
        }
        B.ov.rd.red[c][row][0] = gu0;
        B.ov.rd.red[c][row][1] = gu1;
        B.ov.rd.red[c][row][2] = gu2;
        B.ov.rd.red[c][row][3] = gfcp;
    }
    __syncthreads();

    // ---------------- P7: final combine + scatter (chunk 0 lanes) ----------------
    float gd0 = 0.f, gd1 = 0.f, gd2 = 0.f, eij = 0.f;
    if (act && c == 0) {
        float out = b3[0], gfc = 0.f, gr = 0.f;
        float g0 = 0.f, g1 = 0.f, g2 = 0.f;
#pragma unroll
        for (int cc = 0; cc < 4; cc++) {
            gr  += B.ov.rd.red2[cc][row][0];
            gfc += B.ov.rd.red2[cc][row][1] + B.ov.rd.red[cc][row][3];
            out += B.ov.rd.red2[cc][row][2];
            g0  += B.ov.rd.red[cc][row][0];
            g1  += B.ov.rd.red[cc][row][1];
            g2  += B.ov.rd.red[cc][row][2];
        }
        gfc += out;                         // d(eij)/d(fc) direct term
        eij = out * fc;
        float grf = gr + gfc * (-0.5f * k1 * sa);
        float gdot = g0 * u0 + g1 * u1 + g2 * u2;
        gd0 = grf * u0 + (g0 - gdot * u0) * rinv;
        gd1 = grf * u1 + (g1 - gdot * u1) * rinv;
        gd2 = grf * u2 + (g2 - gdot * u2) * rinv;
        atomicAdd(&gx[j * 3 + 0], -gd0);
        atomicAdd(&gx[j * 3 + 1], -gd1);
        atomicAdd(&gx[j * 3 + 2], -gd2);
    }
    if (wslot == 0) {
#pragma unroll
        for (int off = 16; off > 0; off >>= 1) {
            gd0 += __shfl_xor(gd0, off, 32);
            gd1 += __shfl_xor(gd1, off, 32);
            gd2 += __shfl_xor(gd2, off, 32);
            eij += __shfl_xor(eij, off, 32);
        }
        if (lane == 0) {
            atomicAdd(&gx[atom * 3 + 0], gd0);
            atomicAdd(&gx[atom * 3 + 1], gd1);
            atomicAdd(&gx[atom * 3 + 2], gd2);
            e_atom[atom] = eij;
        }
    }
}

// blocks 0..7: per-config energy reduction; blocks 8..: forces = -gx
extern "C" __global__ void __launch_bounds__(256)
fit_finalize(const float* __restrict__ e_atom, const float* __restrict__ gx,
             float* __restrict__ out)
{
    int b = blockIdx.x;
    if (b < NCONF) {
        __shared__ float red[256];
        int t = threadIdx.x;
        red[t] = (t < APC) ? e_atom[b * APC + t] : 0.f;
        __syncthreads();
        for (int s = 128; s > 0; s >>= 1) {
            if (t < s) red[t] += red[t + s];
            __syncthreads();
        }
        if (t == 0) out[b] = red[0];
    } else {
        int idx = (b - NCONF) * 256 + threadIdx.x;
        if (idx < NATOMS * 3) out[NCONF + idx] = -gx[idx];
    }
}

extern "C" void kernel_launch(void* const* d_in, const int* in_sizes, int n_in,
                              void* d_out, int out_size, void* d_ws, size_t ws_size,
                              hipStream_t stream)
{
    const float* x  = (const float*)d_in[0];
    const float* tx = (const float*)d_in[1];
    const int*   uj = (const int*)d_in[7];
    const float* W1 = (const float*)d_in[8];
    const float* b1 = (const float*)d_in[9];
    const float* W2 = (const float*)d_in[10];
    const float* b2 = (const float*)d_in[11];
    const float* W3 = (const float*)d_in[12];
    const float* b3 = (const float*)d_in[13];

    float* gx     = (float*)d_ws;           // [NATOMS*3]
    float* e_atom = gx + NATOMS * 3;        // [NATOMS]

    hipMemsetAsync(gx, 0, NATOMS * 3 * sizeof(float), stream);

    fit_main<<<NATOMS / 2, 256, 0, stream>>>(x, tx, uj, W1, b1, W2, b2, W3, b3,
                                             gx, e_atom);

    int fblocks = NCONF + (NATOMS * 3 + 255) / 256;   // 8 + 24
    fit_finalize<<<fblocks, 256, 0, stream>>>(e_atom, gx, (float*)d_out);
}

// Round 4
// 149.126 us; speedup vs baseline: 2.9152x; 2.9152x over previous
//
#include <hip/hip_runtime.h>
#include <math.h>

#define NATOMS 2000
#define NNBR   30
#define NCONF  8
#define APC    250
#define NRAD   12
#define M3     20
#define H1N    64
#define H2N    32

#define MU(m) (-1.0f + (float)(m) * (2.0f / 19.0f))

__device__ __forceinline__ float sigmoidf(float v) {
    return 1.0f / (1.0f + __expf(-v));
}

// Per-atom shared buffers. Union overlays phase-disjoint data.
struct AtomBuf {
    float u[NNBR][3];
    float fcb[NNBR];
    float h1[NNBR][65];      // z1 sigmoid fwd; overwritten with g_z1 in P4
    float gd3[NNBR][25];     // dE/d(d3[m]) per row
    union {
        float d3w[2][NNBR][21];
        float gz2[NNBR][33];
        struct { float red[4][NNBR][4]; float red2[4][NNBR][4]; } rd;
    } ov;
};

// 256 threads = 4 waves = 2 atoms x 2 waves.
// chunk c = wslot*2+half splits q-loop {8,8,7,7}, h-dim 16, k-dim 8, d-dim 8.
extern "C" __global__ void __launch_bounds__(256)
fit_main(const float* __restrict__ x, const float* __restrict__ tx,
         const int* __restrict__ uj,
         const float* __restrict__ W1, const float* __restrict__ b1,
         const float* __restrict__ W2, const float* __restrict__ b2,
         const float* __restrict__ W3, const float* __restrict__ b3,
         float* __restrict__ gx, float* __restrict__ e_atom)
{
    __shared__ AtomBuf ab[2];

    const int tid    = threadIdx.x;
    const int sub    = tid >> 7;
    const int wslot  = (tid >> 6) & 1;
    const int lane   = tid & 63;
    const int half   = lane >> 5;
    const int row    = lane & 31;
    const int c      = wslot * 2 + half;
    const int atom   = blockIdx.x * 2 + sub;
    const bool act   = (row < NNBR);
    AtomBuf& B = ab[sub];

    const float k1  = 0.6283185307179586f;   // pi/5
    const float sq  = 0.6324555320336759f;   // sqrt(2/5)
    const float eta = 45.125f;               // 1/(2*dmu^2), dmu=2/19
    const float RHO = 0.36787944117144233f;  // exp(-1) = ratio-of-ratios
    const float C2  = -90.25f;               // -2*eta

    const int qn    = (c >= 2) ? 7 : 8;
    const int q0    = c * 8 - ((c == 3) ? 1 : 0);
    const int hbase = c * 16;
    const int kbase = c * 8;
    const int dbase = c * 8;

    // ---------------- P0: pair geometry (redundant per chunk) ----------------
    float r = 1.f, rinv = 1.f, u0 = 0.f, u1 = 0.f, u2 = 0.f;
    float fc = 0.f, ca = 1.f, sa = 0.f;
    int j = 0;
    if (act) {
        int p = atom * NNBR + row;
        j = uj[p];
        float d0 = x[atom * 3 + 0] - x[j * 3 + 0] - tx[p * 3 + 0];
        float d1 = x[atom * 3 + 1] - x[j * 3 + 1] - tx[p * 3 + 1];
        float d2 = x[atom * 3 + 2] - x[j * 3 + 2] - tx[p * 3 + 2];
        r = sqrtf(d0 * d0 + d1 * d1 + d2 * d2);
        rinv = 1.0f / r;
        u0 = d0 * rinv; u1 = d1 * rinv; u2 = d2 * rinv;
        __sincosf(k1 * r, &sa, &ca);
        fc = 0.5f * (ca + 1.0f);
        if (c == 0) {
            B.u[row][0] = u0; B.u[row][1] = u1; B.u[row][2] = u2;
            B.fcb[row] = fc;
        }
    }
    __syncthreads();

    // ---------------- P1: 3-body forward (q-chunked, 3-exp sweep) ----------------
    float d3p[M3];
#pragma unroll
    for (int m = 0; m < M3; m++) d3p[m] = 0.f;
    if (act) {
        for (int qq = 0; qq < qn; qq++) {
            int q = q0 + qq;
            float vq0 = B.u[q][0], vq1 = B.u[q][1], vq2 = B.u[q][2];
            float fq = (q == row) ? 0.f : B.fcb[q];
            float cs = u0 * vq0 + u1 * vq1 + u2 * vq2;
            float E  = __expf(9.5f * cs);
            float Ei = __expf(-9.5f * cs);
            float t9 = cs - MU(9);
            float h9 = __expf(-eta * t9 * t9);
            // ascending m=10..19: h10 = h9*E, r10 = E*RHO
            {
                float h = h9 * E, rr = E * RHO;
                d3p[10] = fmaf(fq, h, d3p[10]);
#pragma unroll
                for (int m = 11; m < 20; m++) {
                    h *= rr; rr *= RHO;
                    d3p[m] = fmaf(fq, h, d3p[m]);
                }
            }
            // descending m=9..0: s9 = RHO*Ei
            {
                float h = h9, rr = RHO * Ei;
                d3p[9] = fmaf(fq, h, d3p[9]);
#pragma unroll
                for (int m = 8; m >= 0; m--) {
                    h *= rr; rr *= RHO;
                    d3p[m] = fmaf(fq, h, d3p[m]);
                }
            }
        }
    }
#pragma unroll
    for (int m = 0; m < M3; m++) d3p[m] += __shfl_xor(d3p[m], 32);
    if (act && half == 0) {
#pragma unroll
        for (int m = 0; m < M3; m++) B.ov.d3w[wslot][row][m] = d3p[m];
    }
    __syncthreads();

    // ---------------- P2: layer1 forward (h-chunk of 16) ----------------
    float h1v[16];
    if (act) {
#pragma unroll
        for (int t = 0; t < 4; t++) {
            float4 v = *(const float4*)&b1[hbase + 4 * t];
            h1v[4 * t + 0] = v.x; h1v[4 * t + 1] = v.y;
            h1v[4 * t + 2] = v.z; h1v[4 * t + 3] = v.w;
        }
        float sprev = 0.f, scur = sa;
        float coef = fc * sq * rinv;
        for (int d = 0; d < NRAD; d++) {
            float rb = coef * scur;
#pragma unroll
            for (int t = 0; t < 4; t++) {
                float4 w = *(const float4*)&W1[d * H1N + hbase + 4 * t];
                h1v[4 * t + 0] = fmaf(rb, w.x, h1v[4 * t + 0]);
                h1v[4 * t + 1] = fmaf(rb, w.y, h1v[4 * t + 1]);
                h1v[4 * t + 2] = fmaf(rb, w.z, h1v[4 * t + 2]);
                h1v[4 * t + 3] = fmaf(rb, w.w, h1v[4 * t + 3]);
            }
            float snext = 2.f * ca * scur - sprev; sprev = scur; scur = snext;
        }
#pragma unroll
        for (int m = 0; m < M3; m++) {
            float dv = B.ov.d3w[0][row][m] + B.ov.d3w[1][row][m];
#pragma unroll
            for (int t = 0; t < 4; t++) {
                float4 w = *(const float4*)&W1[(NRAD + m) * H1N + hbase + 4 * t];
                h1v[4 * t + 0] = fmaf(dv, w.x, h1v[4 * t + 0]);
                h1v[4 * t + 1] = fmaf(dv, w.y, h1v[4 * t + 1]);
                h1v[4 * t + 2] = fmaf(dv, w.z, h1v[4 * t + 2]);
                h1v[4 * t + 3] = fmaf(dv, w.w, h1v[4 * t + 3]);
            }
        }
#pragma unroll
        for (int hh = 0; hh < 16; hh++) h1v[hh] = sigmoidf(h1v[hh]);
#pragma unroll
        for (int hh = 0; hh < 16; hh++) B.h1[row][hbase + hh] = h1v[hh];
    }
    __syncthreads();

    // ---------------- P3: layer2 forward (k-chunk of 8) ----------------
    float outp = 0.f;
    if (act) {
        float acc[8];
#pragma unroll
        for (int kk = 0; kk < 8; kk++) acc[kk] = b2[kbase + kk];
        for (int h = 0; h < H1N; h++) {
            float hv = B.h1[row][h];
            const float4* wp = (const float4*)&W2[h * H2N + kbase];
            float4 wa = wp[0], wb = wp[1];
            acc[0] = fmaf(hv, wa.x, acc[0]); acc[1] = fmaf(hv, wa.y, acc[1]);
            acc[2] = fmaf(hv, wa.z, acc[2]); acc[3] = fmaf(hv, wa.w, acc[3]);
            acc[4] = fmaf(hv, wb.x, acc[4]); acc[5] = fmaf(hv, wb.y, acc[5]);
            acc[6] = fmaf(hv, wb.z, acc[6]); acc[7] = fmaf(hv, wb.w, acc[7]);
        }
#pragma unroll
        for (int kk = 0; kk < 8; kk++) {
            float s = sigmoidf(acc[kk]);
            float w3 = W3[kbase + kk];
            outp = fmaf(s, w3, outp);
            B.ov.gz2[row][kbase + kk] = fc * w3 * s * (1.f - s);
        }
    }
    __syncthreads();

    // ---------------- P4: layer2 backward -> g_z1 (h-chunk) ----------------
    if (act) {
        float gh1[16];
#pragma unroll
        for (int hh = 0; hh < 16; hh++) gh1[hh] = 0.f;
#pragma unroll
        for (int kb = 0; kb < 2; kb++) {
            float g16[16];
#pragma unroll
            for (int t = 0; t < 16; t++) g16[t] = B.ov.gz2[row][kb * 16 + t];
#pragma unroll
            for (int hh = 0; hh < 16; hh++) {
                int h = hbase + hh;
                const float4* wp = (const float4*)&W2[h * H2N + kb * 16];
                float4 wa = wp[0], wb = wp[1], wc = wp[2], wd = wp[3];
                float a = gh1[hh];
                a = fmaf(g16[0],  wa.x, a); a = fmaf(g16[1],  wa.y, a);
                a = fmaf(g16[2],  wa.z, a); a = fmaf(g16[3],  wa.w, a);
                a = fmaf(g16[4],  wb.x, a); a = fmaf(g16[5],  wb.y, a);
                a = fmaf(g16[6],  wb.z, a); a = fmaf(g16[7],  wb.w, a);
                a = fmaf(g16[8],  wc.x, a); a = fmaf(g16[9],  wc.y, a);
                a = fmaf(g16[10], wc.z, a); a = fmaf(g16[11], wc.w, a);
                a = fmaf(g16[12], wd.x, a); a = fmaf(g16[13], wd.y, a);
                a = fmaf(g16[14], wd.z, a); a = fmaf(g16[15], wd.w, a);
                gh1[hh] = a;
            }
        }
#pragma unroll
        for (int hh = 0; hh < 16; hh++) {
            float hv = h1v[hh];
            gh1[hh] = gh1[hh] * hv * (1.f - hv);
        }
#pragma unroll
        for (int hh = 0; hh < 16; hh++) B.h1[row][hbase + hh] = gh1[hh];
    }
    __syncthreads();

    // ---------------- P5: layer1 backward (d-chunk of 8) ----------------
    if (act) {
        float gd[8];
#pragma unroll
        for (int dd = 0; dd < 8; dd++) gd[dd] = 0.f;
#pragma unroll
        for (int hb = 0; hb < 4; hb++) {
            float g16[16];
#pragma unroll
            for (int t = 0; t < 16; t++) g16[t] = B.h1[row][hb * 16 + t];
#pragma unroll
            for (int dd = 0; dd < 8; dd++) {
                int d = dbase + dd;
                const float4* wp = (const float4*)&W1[d * H1N + hb * 16];
                float4 wa = wp[0], wb = wp[1], wc = wp[2], wd = wp[3];
                float a = gd[dd];
                a = fmaf(g16[0],  wa.x, a); a = fmaf(g16[1],  wa.y, a);
                a = fmaf(g16[2],  wa.z, a); a = fmaf(g16[3],  wa.w, a);
                a = fmaf(g16[4],  wb.x, a); a = fmaf(g16[5],  wb.y, a);
                a = fmaf(g16[6],  wb.z, a); a = fmaf(g16[7],  wb.w, a);
                a = fmaf(g16[8],  wc.x, a); a = fmaf(g16[9],  wc.y, a);
                a = fmaf(g16[10], wc.z, a); a = fmaf(g16[11], wc.w, a);
                a = fmaf(g16[12], wd.x, a); a = fmaf(g16[13], wd.y, a);
                a = fmaf(g16[14], wd.z, a); a = fmaf(g16[15], wd.w, a);
                gd[dd] = a;
            }
        }
        float grp = 0.f, gfp = 0.f;
        float scur = 0.f, ccur = 1.f, sprev = 0.f, cprev = 1.f;
        if (dbase < NRAD) {
            __sincosf((float)(dbase + 1) * k1 * r, &scur, &ccur);
            sprev = scur * ca - ccur * sa;   // sin((n0-1)*a)
            cprev = ccur * ca + scur * sa;   // cos((n0-1)*a)
        }
#pragma unroll
        for (int dd = 0; dd < 8; dd++) {
            int d = dbase + dd;
            if (d < NRAD) {
                float n = (float)(d + 1);
                grp += gd[dd] * fc * sq * rinv * (n * k1 * ccur - scur * rinv);
                gfp += gd[dd] * sq * scur * rinv;
                float snext = 2.f * ca * scur - sprev; sprev = scur; scur = snext;
                float cnext = 2.f * ca * ccur - cprev; cprev = ccur; ccur = cnext;
            } else {
                B.gd3[row][d - NRAD] = gd[dd];
            }
        }
        B.ov.rd.red2[c][row][0] = grp;
        B.ov.rd.red2[c][row][1] = gfp;
        B.ov.rd.red2[c][row][2] = outp;
    }
    __syncthreads();

    // ---------------- P6: 3-body backward (q-chunked, 3-exp sweep) ----------------
    if (act) {
        float A[M3];
#pragma unroll
        for (int m = 0; m < M3; m++) A[m] = B.gd3[row][m];
        float gu0 = 0.f, gu1 = 0.f, gu2 = 0.f, gfcp = 0.f;
        for (int qq = 0; qq < qn; qq++) {
            int q = q0 + qq;
            float vq0 = B.u[q][0], vq1 = B.u[q][1], vq2 = B.u[q][2];
            float fq = B.fcb[q];
            float cs = u0 * vq0 + u1 * vq1 + u2 * vq2;
            float E  = __expf(9.5f * cs);
            float Ei = __expf(-9.5f * cs);
            float t9 = cs - MU(9);
            float h9 = __expf(-eta * t9 * t9);
            float sA = 0.f, sB = 0.f, sG = 0.f;
            // ascending m=10..19
            {
                float h = h9 * E, rr = E * RHO;
#pragma unroll
                for (int m = 10; m < 20; m++) {
                    if (m > 10) { h *= rr; rr *= RHO; }
                    float t = cs - MU(m);
                    float de = C2 * t * h;
                    float Bm = B.gd3[q][m];
                    sA = fmaf(A[m], de, sA);
                    sB = fmaf(Bm, de, sB);
                    sG = fmaf(Bm, h, sG);
                }
            }
            // descending m=9..0
            {
                float h = h9, rr = RHO * Ei;
#pragma unroll
                for (int m = 9; m >= 0; m--) {
                    if (m < 9) { h *= rr; rr *= RHO; }
                    float t = cs - MU(m);
                    float de = C2 * t * h;
                    float Bm = B.gd3[q][m];
                    sA = fmaf(A[m], de, sA);
                    sB = fmaf(Bm, de, sB);
                    sG = fmaf(Bm, h, sG);
                }
            }
            if (q != row) {
                gfcp += sG;
                float gcos = fq * sA + fc * sB;
                gu0 = fmaf(gcos, vq0, gu0);
                gu1 = fmaf(gcos, vq1, gu1);
                gu2 = fmaf(gcos, vq2, gu2);
            }
        }
        B.ov.rd.red[c][row][0] = gu0;
        B.ov.rd.red[c][row][1] = gu1;
        B.ov.rd.red[c][row][2] = gu2;
        B.ov.rd.red[c][row][3] = gfcp;
    }
    __syncthreads();

    // ---------------- P7: final combine + scatter (chunk 0 lanes) ----------------
    float gd0 = 0.f, gd1 = 0.f, gd2 = 0.f, eij = 0.f;
    if (act && c == 0) {
        float out = b3[0], gfc = 0.f, gr = 0.f;
        float g0 = 0.f, g1 = 0.f, g2 = 0.f;
#pragma unroll
        for (int cc = 0; cc < 4; cc++) {
            gr  += B.ov.rd.red2[cc][row][0];
            gfc += B.ov.rd.red2[cc][row][1] + B.ov.rd.red[cc][row][3];
            out += B.ov.rd.red2[cc][row][2];
            g0  += B.ov.rd.red[cc][row][0];
            g1  += B.ov.rd.red[cc][row][1];
            g2  += B.ov.rd.red[cc][row][2];
        }
        gfc += out;
        eij = out * fc;
        float grf = gr + gfc * (-0.5f * k1 * sa);
        float gdot = g0 * u0 + g1 * u1 + g2 * u2;
        gd0 = grf * u0 + (g0 - gdot * u0) * rinv;
        gd1 = grf * u1 + (g1 - gdot * u1) * rinv;
        gd2 = grf * u2 + (g2 - gdot * u2) * rinv;
        atomicAdd(&gx[j * 3 + 0], -gd0);
        atomicAdd(&gx[j * 3 + 1], -gd1);
        atomicAdd(&gx[j * 3 + 2], -gd2);
    }
    if (wslot == 0) {
#pragma unroll
        for (int off = 16; off > 0; off >>= 1) {
            gd0 += __shfl_xor(gd0, off, 32);
            gd1 += __shfl_xor(gd1, off, 32);
            gd2 += __shfl_xor(gd2, off, 32);
            eij += __shfl_xor(eij, off, 32);
        }
        if (lane == 0) {
            atomicAdd(&gx[atom * 3 + 0], gd0);
            atomicAdd(&gx[atom * 3 + 1], gd1);
            atomicAdd(&gx[atom * 3 + 2], gd2);
            e_atom[atom] = eij;
        }
    }
}

// blocks 0..7: per-config energy reduction; blocks 8..: forces = -gx
extern "C" __global__ void __launch_bounds__(256)
fit_finalize(const float* __restrict__ e_atom, const float* __restrict__ gx,
             float* __restrict__ out)
{
    int b = blockIdx.x;
    if (b < NCONF) {
        __shared__ float red[256];
        int t = threadIdx.x;
        red[t] = (t < APC) ? e_atom[b * APC + t] : 0.f;
        __syncthreads();
        for (int s = 128; s > 0; s >>= 1) {
            if (t < s) red[t] += red[t + s];
            __syncthreads();
        }
        if (t == 0) out[b] = red[0];
    } else {
        int idx = (b - NCONF) * 256 + threadIdx.x;
        if (idx < NATOMS * 3) out[NCONF + idx] = -gx[idx];
    }
}

extern "C" void kernel_launch(void* const* d_in, const int* in_sizes, int n_in,
                              void* d_out, int out_size, void* d_ws, size_t ws_size,
                              hipStream_t stream)
{
    const float* x  = (const float*)d_in[0];
    const float* tx = (const float*)d_in[1];
    const int*   uj = (const int*)d_in[7];
    const float* W1 = (const float*)d_in[8];
    const float* b1 = (const float*)d_in[9];
    const float* W2 = (const float*)d_in[10];
    const float* b2 = (const float*)d_in[11];
    const float* W3 = (const float*)d_in[12];
    const float* b3 = (const float*)d_in[13];

    float* gx     = (float*)d_ws;           // [NATOMS*3]
    float* e_atom = gx + NATOMS * 3;        // [NATOMS]

    hipMemsetAsync(gx, 0, NATOMS * 3 * sizeof(float), stream);

    fit_main<<<NATOMS / 2, 256, 0, stream>>>(x, tx, uj, W1, b1, W2, b2, W3, b3,
                                             gx, e_atom);

    int fblocks = NCONF + (NATOMS * 3 + 255) / 256;   // 8 + 24
    fit_finalize<<<fblocks, 256, 0, stream>>>(e_atom, gx, (float*)d_out);
}

// Round 5
// 75.076 us; speedup vs baseline: 5.7906x; 1.9863x over previous
//
#include <hip/hip_runtime.h>
#include <math.h>

#define NATOMS 2000
#define NNBR   30
#define NCONF  8
#define APC    250
#define NRAD   12
#define M3     20
#define H1N    64
#define H2N    32

#define MU(m) (-1.0f + (float)(m) * (2.0f / 19.0f))

__device__ __forceinline__ float sigmoidf(float v) {
    return 1.0f / (1.0f + __expf(-v));
}

// One atom per 256-thread block. Lanes flattened over (pair, feature):
//   L1 fwd : task (p,h)  - 64 lanes = h, waves stride p
//   L2 fwd : task (p,k,half)
//   gz1    : task (p,h)
//   gd     : task (p,d,half)
//   3body  : tasks (p,m) fwd / (p,q) bwd, strided over 256 threads
extern "C" __global__ void __launch_bounds__(256)
fit_main(const float* __restrict__ x, const float* __restrict__ tx,
         const int* __restrict__ uj,
         const float* __restrict__ W1, const float* __restrict__ b1,
         const float* __restrict__ W2, const float* __restrict__ b2,
         const float* __restrict__ W3, const float* __restrict__ b3,
         float* __restrict__ gx, float* __restrict__ e_atom)
{
    const int tid  = threadIdx.x;
    const int lane = tid & 63;
    const int wid  = tid >> 6;
    const int atom = blockIdx.x;

    __shared__ float s_u[NNBR][4];
    __shared__ float s_geo[NNBR][8];          // 0:fc 1:r 2:rinv 3:sa 4:ca 5:z3
    __shared__ int   s_j[NNBR];
    __shared__ __align__(16) float s_desc[NNBR * 36];  // [p][d<32], rows 144B
    __shared__ __align__(16) float s_h1[NNBR * 68];    // h1 fwd, then g_z1 in place
    __shared__ __align__(16) float s_gz2[NNBR * 36];
    __shared__ float s_cos[NNBR * 31];
    __shared__ float s_gd3[NNBR * 21];
    __shared__ float s_gdr[NNBR * 12];
    __shared__ float s_gcos[NNBR * 31];
    __shared__ float s_sG[NNBR * 31];
    __shared__ float s_red[NNBR * 4];
    __shared__ float s_W1[32 * 65];            // [d][h] padded
    __shared__ float s_W2t[32 * 65];           // [k][h] padded

    const float k1  = 0.6283185307179586f;   // pi/5
    const float sq  = 0.6324555320336759f;   // sqrt(2/5)
    const float eta = 45.125f;               // 1/(2*dmu^2), dmu=2/19
    const float C2  = -90.25f;               // -2*eta

    // ---------------- A: stage weights + pair geometry ----------------
#pragma unroll
    for (int i = 0; i < 8; i++) {
        int idx = tid + 256 * i;               // 0..2047
        int d = idx >> 6, h = idx & 63;
        s_W1[d * 65 + h] = W1[idx];
    }
#pragma unroll
    for (int i = 0; i < 8; i++) {
        int idx = tid + 256 * i;
        int h = idx >> 5, k = idx & 31;
        s_W2t[k * 65 + h] = W2[idx];
    }
    if (tid < NNBR) {
        int p = atom * NNBR + tid;
        int j = uj[p];
        float d0 = x[atom * 3 + 0] - x[j * 3 + 0] - tx[p * 3 + 0];
        float d1 = x[atom * 3 + 1] - x[j * 3 + 1] - tx[p * 3 + 1];
        float d2 = x[atom * 3 + 2] - x[j * 3 + 2] - tx[p * 3 + 2];
        float r = sqrtf(d0 * d0 + d1 * d1 + d2 * d2);
        float rinv = 1.0f / r;
        float sa, ca;
        __sincosf(k1 * r, &sa, &ca);
        float fc = 0.5f * (ca + 1.0f);
        s_u[tid][0] = d0 * rinv; s_u[tid][1] = d1 * rinv; s_u[tid][2] = d2 * rinv;
        s_geo[tid][0] = fc; s_geo[tid][1] = r; s_geo[tid][2] = rinv;
        s_geo[tid][3] = sa; s_geo[tid][4] = ca;
        s_j[tid] = j;
    }
    __syncthreads();

    // ---------------- B: cos matrix + radial basis ----------------
#pragma unroll 1
    for (int t = tid; t < NNBR * NNBR; t += 256) {
        int p = t / NNBR, q = t - p * NNBR;
        float cs = s_u[p][0] * s_u[q][0] + s_u[p][1] * s_u[q][1]
                 + s_u[p][2] * s_u[q][2];
        s_cos[p * 31 + q] = cs;
    }
#pragma unroll 1
    for (int t = tid; t < NNBR * NRAD; t += 256) {
        int p = t / NRAD, n = t - p * NRAD;
        float r = s_geo[p][1], rinv = s_geo[p][2], fc = s_geo[p][0];
        float s = __sinf((float)(n + 1) * k1 * r);
        s_desc[p * 36 + n] = fc * sq * s * rinv;
    }
    __syncthreads();

    // ---------------- C: 3-body forward d3[p][m] ----------------
#pragma unroll 1
    for (int t = tid; t < NNBR * M3; t += 256) {
        int p = t / M3, m = t - p * M3;
        float mu = MU(m);
        float a0 = 0.f, a1 = 0.f;
        for (int q = 0; q < NNBR; q += 2) {
            float c0 = s_cos[p * 31 + q],     c1 = s_cos[p * 31 + q + 1];
            float f0 = (q == p) ? 0.f : s_geo[q][0];
            float f1 = (q + 1 == p) ? 0.f : s_geo[q + 1][0];
            float t0 = c0 - mu, t1 = c1 - mu;
            a0 = fmaf(f0, __expf(-eta * t0 * t0), a0);
            a1 = fmaf(f1, __expf(-eta * t1 * t1), a1);
        }
        s_desc[p * 36 + NRAD + m] = a0 + a1;
    }
    __syncthreads();

    // ---------------- D: layer1 forward (task p,h) ----------------
    {
        float w1c[32];
#pragma unroll
        for (int d = 0; d < 32; d++) w1c[d] = s_W1[d * 65 + lane];
        float bias = b1[lane];
#pragma unroll 1
        for (int p = wid; p < NNBR; p += 4) {
            const float4* dp = (const float4*)(s_desc + p * 36);
            float acc = bias;
#pragma unroll
            for (int t4 = 0; t4 < 8; t4++) {
                float4 v = dp[t4];
                acc = fmaf(v.x, w1c[4 * t4 + 0], acc);
                acc = fmaf(v.y, w1c[4 * t4 + 1], acc);
                acc = fmaf(v.z, w1c[4 * t4 + 2], acc);
                acc = fmaf(v.w, w1c[4 * t4 + 3], acc);
            }
            s_h1[p * 68 + lane] = sigmoidf(acc);
        }
    }
    __syncthreads();

    // ---------------- E: layer2 forward + z3 + gz2 (task p,k,half) ----------------
    {
        const int k = lane & 31;
        const int half = lane >> 5;
        float w2c[32];
#pragma unroll
        for (int i = 0; i < 32; i++) w2c[i] = s_W2t[k * 65 + half * 32 + i];
        float w3k = W3[k];
        float b2k = b2[k];
        float b3v = b3[0];
#pragma unroll 1
        for (int p = wid; p < NNBR; p += 4) {
            const float4* hp = (const float4*)(s_h1 + p * 68 + half * 32);
            float acc = 0.f;
#pragma unroll
            for (int t4 = 0; t4 < 8; t4++) {
                float4 v = hp[t4];
                acc = fmaf(v.x, w2c[4 * t4 + 0], acc);
                acc = fmaf(v.y, w2c[4 * t4 + 1], acc);
                acc = fmaf(v.z, w2c[4 * t4 + 2], acc);
                acc = fmaf(v.w, w2c[4 * t4 + 3], acc);
            }
            acc += __shfl_xor(acc, 32);
            float s = sigmoidf(b2k + acc);
            if (half == 0) {
                float fcp = s_geo[p][0];
                s_gz2[p * 36 + k] = fcp * w3k * s * (1.f - s);
            }
            float sw = (half == 0) ? s * w3k : 0.f;
            sw += __shfl_xor(sw, 16);
            sw += __shfl_xor(sw, 8);
            sw += __shfl_xor(sw, 4);
            sw += __shfl_xor(sw, 2);
            sw += __shfl_xor(sw, 1);
            if (lane == 0) s_geo[p][5] = b3v + sw;
        }
    }
    __syncthreads();

    // ---------------- G: layer2 backward -> g_z1 in place (task p,h) ----------------
    {
        float w2r[32];
#pragma unroll
        for (int kk = 0; kk < 32; kk++) w2r[kk] = s_W2t[kk * 65 + lane];
#pragma unroll 1
        for (int p = wid; p < NNBR; p += 4) {
            const float4* gp = (const float4*)(s_gz2 + p * 36);
            float acc = 0.f;
#pragma unroll
            for (int t4 = 0; t4 < 8; t4++) {
                float4 v = gp[t4];
                acc = fmaf(v.x, w2r[4 * t4 + 0], acc);
                acc = fmaf(v.y, w2r[4 * t4 + 1], acc);
                acc = fmaf(v.z, w2r[4 * t4 + 2], acc);
                acc = fmaf(v.w, w2r[4 * t4 + 3], acc);
            }
            float hv = s_h1[p * 68 + lane];
            s_h1[p * 68 + lane] = acc * hv * (1.f - hv);
        }
    }
    __syncthreads();

    // ---------------- H: layer1 backward gd[p][d] (task p,d,half) ----------------
    {
        const int d = lane & 31;
        const int half = lane >> 5;
        float w1r[32];
#pragma unroll
        for (int i = 0; i < 32; i++) w1r[i] = s_W1[d * 65 + half * 32 + i];
#pragma unroll 1
        for (int p = wid; p < NNBR; p += 4) {
            const float4* gp = (const float4*)(s_h1 + p * 68 + half * 32);
            float acc = 0.f;
#pragma unroll
            for (int t4 = 0; t4 < 8; t4++) {
                float4 v = gp[t4];
                acc = fmaf(v.x, w1r[4 * t4 + 0], acc);
                acc = fmaf(v.y, w1r[4 * t4 + 1], acc);
                acc = fmaf(v.z, w1r[4 * t4 + 2], acc);
                acc = fmaf(v.w, w1r[4 * t4 + 3], acc);
            }
            acc += __shfl_xor(acc, 32);
            if (half == 0) {
                if (d < NRAD) s_gdr[p * 12 + d] = acc;
                else          s_gd3[p * 21 + (d - NRAD)] = acc;
            }
        }
    }
    __syncthreads();

    // ---------------- I: 3-body backward (task p,q) ----------------
#pragma unroll 1
    for (int t = tid; t < NNBR * NNBR; t += 256) {
        int p = t / NNBR, q = t - p * NNBR;
        float cs = s_cos[p * 31 + q];
        float fcp = s_geo[p][0], fq = s_geo[q][0];
        float sA = 0.f, sB = 0.f, sG = 0.f;
#pragma unroll
        for (int m = 0; m < M3; m++) {
            float tt = cs - MU(m);
            float e = __expf(-eta * tt * tt);
            float de = C2 * tt * e;
            float Ap = s_gd3[p * 21 + m];
            float Bq = s_gd3[q * 21 + m];
            sA = fmaf(Ap, de, sA);
            sB = fmaf(Bq, de, sB);
            sG = fmaf(Bq, e, sG);
        }
        bool diag = (p == q);
        s_gcos[p * 31 + q] = diag ? 0.f : (fq * sA + fcp * sB);
        s_sG[p * 31 + q]   = diag ? 0.f : sG;
    }
    __syncthreads();

    // ---------------- J: reduce gu / gfc over q (task p,c) ----------------
    if (tid < NNBR * 4) {
        int p = tid >> 2, c = tid & 3;
        float acc = 0.f;
        for (int q = 0; q < NNBR; q++) {
            float w = (c == 3) ? s_sG[p * 31 + q] : s_gcos[p * 31 + q];
            float f = (c == 3) ? 1.f : s_u[q][c];
            acc = fmaf(w, f, acc);
        }
        s_red[p * 4 + c] = acc;
    }
    __syncthreads();

    // ---------------- K: rbf backward + final per-pair + scatter ----------------
    float gd0 = 0.f, gd1 = 0.f, gd2 = 0.f, eij = 0.f;
    if (tid < NNBR) {
        float fc = s_geo[tid][0], rinv = s_geo[tid][2];
        float sa = s_geo[tid][3], ca = s_geo[tid][4];
        float out = s_geo[tid][5];
        float u0 = s_u[tid][0], u1 = s_u[tid][1], u2 = s_u[tid][2];
        int j = s_j[tid];
        float grp = 0.f, gfp = 0.f;
        float sprev = 0.f, scur = sa, cprev = 1.f, ccur = ca;
#pragma unroll
        for (int d = 0; d < NRAD; d++) {
            float gdv = s_gdr[tid * 12 + d];
            float n = (float)(d + 1);
            grp += gdv * fc * sq * rinv * (n * k1 * ccur - scur * rinv);
            gfp += gdv * sq * scur * rinv;
            float snext = 2.f * ca * scur - sprev; sprev = scur; scur = snext;
            float cnext = 2.f * ca * ccur - cprev; cprev = ccur; ccur = cnext;
        }
        float gfc = gfp + s_red[tid * 4 + 3] + out;
        float gu0 = s_red[tid * 4 + 0];
        float gu1 = s_red[tid * 4 + 1];
        float gu2 = s_red[tid * 4 + 2];
        float grf = grp + gfc * (-0.5f * k1 * sa);
        float gdot = gu0 * u0 + gu1 * u1 + gu2 * u2;
        gd0 = grf * u0 + (gu0 - gdot * u0) * rinv;
        gd1 = grf * u1 + (gu1 - gdot * u1) * rinv;
        gd2 = grf * u2 + (gu2 - gdot * u2) * rinv;
        atomicAdd(&gx[j * 3 + 0], -gd0);
        atomicAdd(&gx[j * 3 + 1], -gd1);
        atomicAdd(&gx[j * 3 + 2], -gd2);
        eij = out * fc;
    }
    if (wid == 0) {
#pragma unroll
        for (int off = 32; off > 0; off >>= 1) {
            gd0 += __shfl_xor(gd0, off);
            gd1 += __shfl_xor(gd1, off);
            gd2 += __shfl_xor(gd2, off);
            eij += __shfl_xor(eij, off);
        }
        if (tid == 0) {
            atomicAdd(&gx[atom * 3 + 0], gd0);
            atomicAdd(&gx[atom * 3 + 1], gd1);
            atomicAdd(&gx[atom * 3 + 2], gd2);
            e_atom[atom] = eij;
        }
    }
}

// blocks 0..7: per-config energy reduction; blocks 8..: forces = -gx
extern "C" __global__ void __launch_bounds__(256)
fit_finalize(const float* __restrict__ e_atom, const float* __restrict__ gx,
             float* __restrict__ out)
{
    int b = blockIdx.x;
    if (b < NCONF) {
        __shared__ float red[256];
        int t = threadIdx.x;
        red[t] = (t < APC) ? e_atom[b * APC + t] : 0.f;
        __syncthreads();
        for (int s = 128; s > 0; s >>= 1) {
            if (t < s) red[t] += red[t + s];
            __syncthreads();
        }
        if (t == 0) out[b] = red[0];
    } else {
        int idx = (b - NCONF) * 256 + threadIdx.x;
        if (idx < NATOMS * 3) out[NCONF + idx] = -gx[idx];
    }
}

extern "C" void kernel_launch(void* const* d_in, const int* in_sizes, int n_in,
                              void* d_out, int out_size, void* d_ws, size_t ws_size,
                              hipStream_t stream)
{
    const float* x  = (const float*)d_in[0];
    const float* tx = (const float*)d_in[1];
    const int*   uj = (const int*)d_in[7];
    const float* W1 = (const float*)d_in[8];
    const float* b1 = (const float*)d_in[9];
    const float* W2 = (const float*)d_in[10];
    const float* b2 = (const float*)d_in[11];
    const float* W3 = (const float*)d_in[12];
    const float* b3 = (const float*)d_in[13];

    float* gx     = (float*)d_ws;           // [NATOMS*3]
    float* e_atom = gx + NATOMS * 3;        // [NATOMS]

    hipMemsetAsync(gx, 0, NATOMS * 3 * sizeof(float), stream);

    fit_main<<<NATOMS, 256, 0, stream>>>(x, tx, uj, W1, b1, W2, b2, W3, b3,
                                         gx, e_atom);

    int fblocks = NCONF + (NATOMS * 3 + 255) / 256;   // 8 + 24
    fit_finalize<<<fblocks, 256, 0, stream>>>(e_atom, gx, (float*)d_out);
}

// Round 7
// 74.737 us; speedup vs baseline: 5.8169x; 1.0045x over previous
//
#include <hip/hip_runtime.h>
#include <math.h>

#define NATOMS 2000
#define NNBR   30
#define NCONF  8
#define APC    250
#define NRAD   12
#define M3     20
#define H1N    64
#define H2N    32

#define MU(m) (-1.0f + (float)(m) * (2.0f / 19.0f))

__device__ __forceinline__ float sigmoidf(float v) {
    return 1.0f / (1.0f + __expf(-v));
}

// One atom per 256-thread block, phases task-parallel over (pair,feature).
// 3-body phases: task (p, q-chunk) x 8 chunks, 3-exp anchored Gaussian
// recurrence, register partials + 8-lane shfl-tree reduction (no atomics).
extern "C" __global__ void __launch_bounds__(256)
fit_main(const float* __restrict__ x, const float* __restrict__ tx,
         const int* __restrict__ uj,
         const float* __restrict__ W1, const float* __restrict__ b1,
         const float* __restrict__ W2, const float* __restrict__ b2,
         const float* __restrict__ W3, const float* __restrict__ b3,
         float* __restrict__ gx, float* __restrict__ e_atom)
{
    const int tid  = threadIdx.x;
    const int lane = tid & 63;
    const int wid  = tid >> 6;
    const int atom = blockIdx.x;

    __shared__ float s_u[NNBR][4];
    __shared__ float s_geo[NNBR][8];          // 0:fc 1:r 2:rinv 3:sa 4:ca 5:z3
    __shared__ int   s_j[NNBR];
    __shared__ float s_cos[NNBR * 32];
    __shared__ __align__(16) float s_rbf[NNBR * 16];
    __shared__ float s_d3[NNBR * 21];
    __shared__ __align__(16) float s_h1[NNBR * 68];   // h1 fwd, g_z1 after G
    __shared__ __align__(16) float s_gz2[NNBR * 36];
    __shared__ float s_gd3[NNBR * 21];
    __shared__ float s_gdr[NNBR * 12];
    __shared__ float s_red[NNBR * 5];
    __shared__ float s_W1[32 * 65];            // [d][h], h stride 65
    __shared__ float s_W2t[32 * 65];           // [k][h], h stride 65 (h<64!)

    const float k1  = 0.6283185307179586f;   // pi/5
    const float sq  = 0.6324555320336759f;   // sqrt(2/5)
    const float eta = 45.125f;               // 1/(2*dmu^2)
    const float RHO = 0.36787944117144233f;  // exp(-1)
    const float C2  = -90.25f;               // -2*eta

    // ---------------- A: stage weights + pair geometry ----------------
#pragma unroll
    for (int i = 0; i < 8; i++) {
        int idx = tid + 256 * i;               // W1 [32][64]
        s_W1[(idx >> 6) * 65 + (idx & 63)] = W1[idx];
    }
#pragma unroll
    for (int i = 0; i < 8; i++) {
        int idx = tid + 256 * i;               // W2 [64][32] -> W2t[k][h]
        s_W2t[(idx & 31) * 65 + (idx >> 5)] = W2[idx];
    }
    if (tid < NNBR) {
        int p = atom * NNBR + tid;
        int j = uj[p];
        float d0 = x[atom * 3 + 0] - x[j * 3 + 0] - tx[p * 3 + 0];
        float d1 = x[atom * 3 + 1] - x[j * 3 + 1] - tx[p * 3 + 1];
        float d2 = x[atom * 3 + 2] - x[j * 3 + 2] - tx[p * 3 + 2];
        float r = sqrtf(d0 * d0 + d1 * d1 + d2 * d2);
        float rinv = 1.0f / r;
        float sa, ca;
        __sincosf(k1 * r, &sa, &ca);
        float fc = 0.5f * (ca + 1.0f);
        s_u[tid][0] = d0 * rinv; s_u[tid][1] = d1 * rinv; s_u[tid][2] = d2 * rinv;
        s_geo[tid][0] = fc; s_geo[tid][1] = r; s_geo[tid][2] = rinv;
        s_geo[tid][3] = sa; s_geo[tid][4] = ca;
        s_j[tid] = j;
    }
    __syncthreads();

    // ---------------- B: cos matrix + rbf ----------------
#pragma unroll 1
    for (int t = tid; t < NNBR * NNBR; t += 256) {
        int p = t / NNBR, q = t - p * NNBR;
        s_cos[p * 32 + q] = s_u[p][0] * s_u[q][0] + s_u[p][1] * s_u[q][1]
                          + s_u[p][2] * s_u[q][2];
    }
#pragma unroll 1
    for (int t = tid; t < NNBR * NRAD; t += 256) {
        int p = t / NRAD, n = t - p * NRAD;
        float s = __sinf((float)(n + 1) * k1 * s_geo[p][1]);
        s_rbf[p * 16 + n] = s_geo[p][0] * sq * s * s_geo[p][2];
    }
    __syncthreads();

    // ------- C: 3-body forward, task (p, chunk of q), shfl-reduced -------
    if (tid < 240) {
        int p = tid >> 3, c = tid & 7;
        int q0 = (c < 6) ? 4 * c : 24 + 3 * (c - 6);
        int qn = (c < 6) ? 4 : 3;
        float d3part[M3];
#pragma unroll
        for (int m = 0; m < M3; m++) d3part[m] = 0.f;
        for (int qq = 0; qq < qn; qq++) {
            int q = q0 + qq;
            float fq = (q == p) ? 0.f : s_geo[q][0];
            float cs = s_cos[p * 32 + q];
            float E  = __expf(9.5f * cs);
            float Ei = __expf(-9.5f * cs);
            float t9 = cs - MU(9);
            float h9 = __expf(-eta * t9 * t9);
            float h = h9 * E, rr = E * RHO;
            d3part[10] = fmaf(fq, h, d3part[10]);
#pragma unroll
            for (int m = 11; m < 20; m++) {
                h *= rr; rr *= RHO;
                d3part[m] = fmaf(fq, h, d3part[m]);
            }
            h = h9; rr = RHO * Ei;
            d3part[9] = fmaf(fq, h, d3part[9]);
#pragma unroll
            for (int m = 8; m >= 0; m--) {
                h *= rr; rr *= RHO;
                d3part[m] = fmaf(fq, h, d3part[m]);
            }
        }
#pragma unroll
        for (int m = 0; m < M3; m++) {
            float v = d3part[m];
            v += __shfl_xor(v, 1);
            v += __shfl_xor(v, 2);
            v += __shfl_xor(v, 4);
            if (c == 0) s_d3[p * 21 + m] = v;
        }
    }
    __syncthreads();

    // ---------------- D: layer1 forward (task p,h) ----------------
    {
        float w1c[32];
#pragma unroll
        for (int d = 0; d < 32; d++) w1c[d] = s_W1[d * 65 + lane];
        float bias = b1[lane];
#pragma unroll 1
        for (int p = wid; p < NNBR; p += 4) {
            const float4* rp = (const float4*)(s_rbf + p * 16);
            float acc = bias;
#pragma unroll
            for (int t4 = 0; t4 < 3; t4++) {
                float4 v = rp[t4];
                acc = fmaf(v.x, w1c[4 * t4 + 0], acc);
                acc = fmaf(v.y, w1c[4 * t4 + 1], acc);
                acc = fmaf(v.z, w1c[4 * t4 + 2], acc);
                acc = fmaf(v.w, w1c[4 * t4 + 3], acc);
            }
            const float* d3p = s_d3 + p * 21;
#pragma unroll
            for (int m = 0; m < M3; m++) acc = fmaf(d3p[m], w1c[NRAD + m], acc);
            s_h1[p * 68 + lane] = sigmoidf(acc);
        }
    }
    __syncthreads();

    // ---------------- E: layer2 forward + z3 + gz2 (task p,k,half) ----------
    {
        const int k = lane & 31;
        const int half = lane >> 5;
        float w2c[32];
#pragma unroll
        for (int i = 0; i < 32; i++) w2c[i] = s_W2t[k * 65 + half * 32 + i];
        float w3k = W3[k];
        float b2k = b2[k];
        float b3v = b3[0];
#pragma unroll 1
        for (int p = wid; p < NNBR; p += 4) {
            const float4* hp = (const float4*)(s_h1 + p * 68 + half * 32);
            float acc = 0.f;
#pragma unroll
            for (int t4 = 0; t4 < 8; t4++) {
                float4 v = hp[t4];
                acc = fmaf(v.x, w2c[4 * t4 + 0], acc);
                acc = fmaf(v.y, w2c[4 * t4 + 1], acc);
                acc = fmaf(v.z, w2c[4 * t4 + 2], acc);
                acc = fmaf(v.w, w2c[4 * t4 + 3], acc);
            }
            acc += __shfl_xor(acc, 32);
            float s = sigmoidf(b2k + acc);
            if (half == 0) s_gz2[p * 36 + k] = s_geo[p][0] * w3k * s * (1.f - s);
            float sw = (half == 0) ? s * w3k : 0.f;
            sw += __shfl_xor(sw, 16);
            sw += __shfl_xor(sw, 8);
            sw += __shfl_xor(sw, 4);
            sw += __shfl_xor(sw, 2);
            sw += __shfl_xor(sw, 1);
            if (lane == 0) s_geo[p][5] = b3v + sw;
        }
    }
    __syncthreads();

    // ---------------- G: layer2 backward -> g_z1 in place (task p,h) --------
    {
        float w2r[32];
#pragma unroll
        for (int kk = 0; kk < 32; kk++) w2r[kk] = s_W2t[kk * 65 + lane];
#pragma unroll 1
        for (int p = wid; p < NNBR; p += 4) {
            const float4* gp = (const float4*)(s_gz2 + p * 36);
            float acc = 0.f;
#pragma unroll
            for (int t4 = 0; t4 < 8; t4++) {
                float4 v = gp[t4];
                acc = fmaf(v.x, w2r[4 * t4 + 0], acc);
                acc = fmaf(v.y, w2r[4 * t4 + 1], acc);
                acc = fmaf(v.z, w2r[4 * t4 + 2], acc);
                acc = fmaf(v.w, w2r[4 * t4 + 3], acc);
            }
            float hv = s_h1[p * 68 + lane];
            s_h1[p * 68 + lane] = acc * hv * (1.f - hv);
        }
    }
    __syncthreads();

    // ---------------- H: layer1 backward gd[p][d] (task p,d,half) -----------
    {
        const int d = lane & 31;
        const int half = lane >> 5;
        float w1r[32];
#pragma unroll
        for (int i = 0; i < 32; i++) w1r[i] = s_W1[d * 65 + half * 32 + i];
#pragma unroll 1
        for (int p = wid; p < NNBR; p += 4) {
            const float4* gp = (const float4*)(s_h1 + p * 68 + half * 32);
            float acc = 0.f;
#pragma unroll
            for (int t4 = 0; t4 < 8; t4++) {
                float4 v = gp[t4];
                acc = fmaf(v.x, w1r[4 * t4 + 0], acc);
                acc = fmaf(v.y, w1r[4 * t4 + 1], acc);
                acc = fmaf(v.z, w1r[4 * t4 + 2], acc);
                acc = fmaf(v.w, w1r[4 * t4 + 3], acc);
            }
            acc += __shfl_xor(acc, 32);
            if (half == 0) {
                if (d < NRAD) s_gdr[p * 12 + d] = acc;
                else          s_gd3[p * 21 + (d - NRAD)] = acc;
            }
        }
    }
    __syncthreads();

    // ------- I: 3-body backward, task (p, chunk of q), shfl-reduced -------
    if (tid < 240) {
        int p = tid >> 3, c = tid & 7;
        int q0 = (c < 6) ? 4 * c : 24 + 3 * (c - 6);
        int qn = (c < 6) ? 4 : 3;
        float Ap[M3];
#pragma unroll
        for (int m = 0; m < M3; m++) Ap[m] = s_gd3[p * 21 + m];
        float fp_ = s_geo[p][0];
        float gu0 = 0.f, gu1 = 0.f, gu2 = 0.f, gfc = 0.f;
        for (int qq = 0; qq < qn; qq++) {
            int q = q0 + qq;
            float cs = s_cos[p * 32 + q];
            float fq = s_geo[q][0];
            const float* Aq = s_gd3 + q * 21;
            float E  = __expf(9.5f * cs);
            float Ei = __expf(-9.5f * cs);
            float t9 = cs - MU(9);
            float h9 = __expf(-eta * t9 * t9);
            float sAde = 0.f, sBde = 0.f, sBh = 0.f;
            {
                float h = h9 * E, rr = E * RHO;
#pragma unroll
                for (int m = 10; m < 20; m++) {
                    if (m > 10) { h *= rr; rr *= RHO; }
                    float de = C2 * (cs - MU(m)) * h;
                    float aq = Aq[m];
                    sAde = fmaf(Ap[m], de, sAde);
                    sBde = fmaf(aq, de, sBde);
                    sBh  = fmaf(aq, h,  sBh);
                }
            }
            {
                float h = h9, rr = RHO * Ei;
#pragma unroll
                for (int m = 9; m >= 0; m--) {
                    if (m < 9) { h *= rr; rr *= RHO; }
                    float de = C2 * (cs - MU(m)) * h;
                    float aq = Aq[m];
                    sAde = fmaf(Ap[m], de, sAde);
                    sBde = fmaf(aq, de, sBde);
                    sBh  = fmaf(aq, h,  sBh);
                }
            }
            if (q != p) {
                float gcos = fq * sAde + fp_ * sBde;
                gu0 = fmaf(gcos, s_u[q][0], gu0);
                gu1 = fmaf(gcos, s_u[q][1], gu1);
                gu2 = fmaf(gcos, s_u[q][2], gu2);
                gfc += sBh;
            }
        }
        gu0 += __shfl_xor(gu0, 1); gu0 += __shfl_xor(gu0, 2); gu0 += __shfl_xor(gu0, 4);
        gu1 += __shfl_xor(gu1, 1); gu1 += __shfl_xor(gu1, 2); gu1 += __shfl_xor(gu1, 4);
        gu2 += __shfl_xor(gu2, 1); gu2 += __shfl_xor(gu2, 2); gu2 += __shfl_xor(gu2, 4);
        gfc += __shfl_xor(gfc, 1); gfc += __shfl_xor(gfc, 2); gfc += __shfl_xor(gfc, 4);
        if (c == 0) {
            s_red[p * 5 + 0] = gu0;
            s_red[p * 5 + 1] = gu1;
            s_red[p * 5 + 2] = gu2;
            s_red[p * 5 + 3] = gfc;
        }
    }
    __syncthreads();

    // ---------------- K: rbf backward + final per-pair + scatter ------------
    float gd0 = 0.f, gd1 = 0.f, gd2 = 0.f, eij = 0.f;
    if (tid < NNBR) {
        float fc = s_geo[tid][0], rinv = s_geo[tid][2];
        float sa = s_geo[tid][3], ca = s_geo[tid][4];
        float out = s_geo[tid][5];
        float u0 = s_u[tid][0], u1 = s_u[tid][1], u2 = s_u[tid][2];
        int j = s_j[tid];
        float grp = 0.f, gfp = 0.f;
        float sprev = 0.f, scur = sa, cprev = 1.f, ccur = ca;
#pragma unroll
        for (int d = 0; d < NRAD; d++) {
            float gdv = s_gdr[tid * 12 + d];
            float n = (float)(d + 1);
            grp += gdv * fc * sq * rinv * (n * k1 * ccur - scur * rinv);
            gfp += gdv * sq * scur * rinv;
            float snext = 2.f * ca * scur - sprev; sprev = scur; scur = snext;
            float cnext = 2.f * ca * ccur - cprev; cprev = ccur; ccur = cnext;
        }
        float gfc = gfp + s_red[tid * 5 + 3] + out;
        float gu0 = s_red[tid * 5 + 0];
        float gu1 = s_red[tid * 5 + 1];
        float gu2 = s_red[tid * 5 + 2];
        float grf = grp + gfc * (-0.5f * k1 * sa);
        float gdot = gu0 * u0 + gu1 * u1 + gu2 * u2;
        gd0 = grf * u0 + (gu0 - gdot * u0) * rinv;
        gd1 = grf * u1 + (gu1 - gdot * u1) * rinv;
        gd2 = grf * u2 + (gu2 - gdot * u2) * rinv;
        atomicAdd(&gx[j * 3 + 0], -gd0);
        atomicAdd(&gx[j * 3 + 1], -gd1);
        atomicAdd(&gx[j * 3 + 2], -gd2);
        eij = out * fc;
    }
    if (wid == 0) {
#pragma unroll
        for (int off = 32; off > 0; off >>= 1) {
            gd0 += __shfl_xor(gd0, off);
            gd1 += __shfl_xor(gd1, off);
            gd2 += __shfl_xor(gd2, off);
            eij += __shfl_xor(eij, off);
        }
        if (tid == 0) {
            atomicAdd(&gx[atom * 3 + 0], gd0);
            atomicAdd(&gx[atom * 3 + 1], gd1);
            atomicAdd(&gx[atom * 3 + 2], gd2);
            e_atom[atom] = eij;
        }
    }
}

// blocks 0..7: per-config energy reduction; blocks 8..: forces = -gx
extern "C" __global__ void __launch_bounds__(256)
fit_finalize(const float* __restrict__ e_atom, const float* __restrict__ gx,
             float* __restrict__ out)
{
    int b = blockIdx.x;
    if (b < NCONF) {
        __shared__ float red[256];
        int t = threadIdx.x;
        red[t] = (t < APC) ? e_atom[b * APC + t] : 0.f;
        __syncthreads();
        for (int s = 128; s > 0; s >>= 1) {
            if (t < s) red[t] += red[t + s];
            __syncthreads();
        }
        if (t == 0) out[b] = red[0];
    } else {
        int idx = (b - NCONF) * 256 + threadIdx.x;
        if (idx < NATOMS * 3) out[NCONF + idx] = -gx[idx];
    }
}

extern "C" void kernel_launch(void* const* d_in, const int* in_sizes, int n_in,
                              void* d_out, int out_size, void* d_ws, size_t ws_size,
                              hipStream_t stream)
{
    const float* x  = (const float*)d_in[0];
    const float* tx = (const float*)d_in[1];
    const int*   uj = (const int*)d_in[7];
    const float* W1 = (const float*)d_in[8];
    const float* b1 = (const float*)d_in[9];
    const float* W2 = (const float*)d_in[10];
    const float* b2 = (const float*)d_in[11];
    const float* W3 = (const float*)d_in[12];
    const float* b3 = (const float*)d_in[13];

    float* gx     = (float*)d_ws;           // [NATOMS*3]
    float* e_atom = gx + NATOMS * 3;        // [NATOMS]

    hipMemsetAsync(gx, 0, NATOMS * 3 * sizeof(float), stream);

    fit_main<<<NATOMS, 256, 0, stream>>>(x, tx, uj, W1, b1, W2, b2, W3, b3,
                                         gx, e_atom);

    int fblocks = NCONF + (NATOMS * 3 + 255) / 256;   // 8 + 24
    fit_finalize<<<fblocks, 256, 0, stream>>>(e_atom, gx, (float*)d_out);
}

// Round 8
// 66.919 us; speedup vs baseline: 6.4965x; 1.1168x over previous
//
#include <hip/hip_runtime.h>
#include <math.h>

#define NATOMS 2000
#define NNBR   30
#define NCONF  8
#define APC    250
#define NRAD   12
#define M3     20
#define H1N    64
#define H2N    32

#define MU(m) (-1.0f + (float)(m) * (2.0f / 19.0f))

__device__ __forceinline__ float sigmoidf(float v) {
    return 1.0f / (1.0f + __expf(-v));
}

// One atom per 256-thread block, phases task-parallel over (pair,feature).
// LDS unions (phase-disjoint), float4 descriptor streams, 4-way split accs.
extern "C" __global__ void __launch_bounds__(256)
fit_main(const float* __restrict__ x, const float* __restrict__ tx,
         const int* __restrict__ uj,
         const float* __restrict__ W1, const float* __restrict__ b1,
         const float* __restrict__ W2, const float* __restrict__ b2,
         const float* __restrict__ W3, const float* __restrict__ b3,
         float* __restrict__ gx, float* __restrict__ e_atom)
{
    const int tid  = threadIdx.x;
    const int lane = tid & 63;
    const int wid  = tid >> 6;
    const int atom = blockIdx.x;

    __shared__ float s_u[NNBR][4];
    __shared__ float s_geo[NNBR][8];          // 0:fc 1:r 2:rinv 3:sa 4:ca 5:z3
    __shared__ int   s_j[NNBR];
    __shared__ float s_cos[NNBR * 32];
    __shared__ __align__(16) float s_d3g[NNBR * 24];    // d3 (C->D), gd3 (H->I)
    __shared__ __align__(16) float s_rbf_gdr[NNBR * 16];// rbf (B->D), gdr (H->K)
    __shared__ __align__(16) float s_h1[NNBR * 68];     // h1 (D->G), g_z1 (G->H)
    __shared__ __align__(16) float s_gz2_red[NNBR * 36];// gz2 (E->G), red (I->K)
    __shared__ float s_W1[32 * 65];            // [d][h], stride 65
    __shared__ float s_W2t[32 * 65];           // [k][h], stride 65

    const float k1  = 0.6283185307179586f;   // pi/5
    const float sq  = 0.6324555320336759f;   // sqrt(2/5)
    const float eta = 45.125f;               // 1/(2*dmu^2)
    const float RHO = 0.36787944117144233f;  // exp(-1)
    const float C2  = -90.25f;               // -2*eta

    // ---------------- A: stage weights + pair geometry ----------------
#pragma unroll
    for (int i = 0; i < 8; i++) {
        int idx = tid + 256 * i;               // W1 [32][64]
        s_W1[(idx >> 6) * 65 + (idx & 63)] = W1[idx];
    }
#pragma unroll
    for (int i = 0; i < 8; i++) {
        int idx = tid + 256 * i;               // W2 [64][32] -> W2t[k][h]
        s_W2t[(idx & 31) * 65 + (idx >> 5)] = W2[idx];
    }
    if (tid < NNBR) {
        int p = atom * NNBR + tid;
        int j = uj[p];
        float d0 = x[atom * 3 + 0] - x[j * 3 + 0] - tx[p * 3 + 0];
        float d1 = x[atom * 3 + 1] - x[j * 3 + 1] - tx[p * 3 + 1];
        float d2 = x[atom * 3 + 2] - x[j * 3 + 2] - tx[p * 3 + 2];
        float r = sqrtf(d0 * d0 + d1 * d1 + d2 * d2);
        float rinv = 1.0f / r;
        float sa, ca;
        __sincosf(k1 * r, &sa, &ca);
        float fc = 0.5f * (ca + 1.0f);
        s_u[tid][0] = d0 * rinv; s_u[tid][1] = d1 * rinv; s_u[tid][2] = d2 * rinv;
        s_geo[tid][0] = fc; s_geo[tid][1] = r; s_geo[tid][2] = rinv;
        s_geo[tid][3] = sa; s_geo[tid][4] = ca;
        s_j[tid] = j;
    }
    __syncthreads();

    // ---------------- B: cos matrix + rbf ----------------
#pragma unroll 1
    for (int t = tid; t < NNBR * NNBR; t += 256) {
        int p = t / NNBR, q = t - p * NNBR;
        s_cos[p * 32 + q] = s_u[p][0] * s_u[q][0] + s_u[p][1] * s_u[q][1]
                          + s_u[p][2] * s_u[q][2];
    }
#pragma unroll 1
    for (int t = tid; t < NNBR * NRAD; t += 256) {
        int p = t / NRAD, n = t - p * NRAD;
        float s = __sinf((float)(n + 1) * k1 * s_geo[p][1]);
        s_rbf_gdr[p * 16 + n] = s_geo[p][0] * sq * s * s_geo[p][2];
    }
    __syncthreads();

    // ------- C: 3-body forward, task (p, chunk of q), shfl-reduced -------
    if (tid < 240) {
        int p = tid >> 3, c = tid & 7;
        int q0 = (c < 6) ? 4 * c : 24 + 3 * (c - 6);
        int qn = (c < 6) ? 4 : 3;
        float d3part[M3];
#pragma unroll
        for (int m = 0; m < M3; m++) d3part[m] = 0.f;
        for (int qq = 0; qq < qn; qq++) {
            int q = q0 + qq;
            float fq = (q == p) ? 0.f : s_geo[q][0];
            float cs = s_cos[p * 32 + q];
            float E  = __expf(9.5f * cs);
            float Ei = __expf(-9.5f * cs);
            float t9 = cs - MU(9);
            float h9 = __expf(-eta * t9 * t9);
            float h = h9 * E, rr = E * RHO;
            d3part[10] = fmaf(fq, h, d3part[10]);
#pragma unroll
            for (int m = 11; m < 20; m++) {
                h *= rr; rr *= RHO;
                d3part[m] = fmaf(fq, h, d3part[m]);
            }
            h = h9; rr = RHO * Ei;
            d3part[9] = fmaf(fq, h, d3part[9]);
#pragma unroll
            for (int m = 8; m >= 0; m--) {
                h *= rr; rr *= RHO;
                d3part[m] = fmaf(fq, h, d3part[m]);
            }
        }
#pragma unroll
        for (int m = 0; m < M3; m++) {
            float v = d3part[m];
            v += __shfl_xor(v, 1);
            v += __shfl_xor(v, 2);
            v += __shfl_xor(v, 4);
            if (c == 0) s_d3g[p * 24 + m] = v;
        }
    }
    __syncthreads();

    // ---------------- D: layer1 forward (task p,h) ----------------
    {
        float w1c[32];
#pragma unroll
        for (int d = 0; d < 32; d++) w1c[d] = s_W1[d * 65 + lane];
        float bias = b1[lane];
#pragma unroll 1
        for (int p = wid; p < NNBR; p += 4) {
            const float4* rp = (const float4*)(s_rbf_gdr + p * 16);
            const float4* dp = (const float4*)(s_d3g + p * 24);
            float a0 = bias, a1 = 0.f, a2 = 0.f, a3 = 0.f;
            float4 v;
            v = rp[0];
            a0 = fmaf(v.x, w1c[0], a0); a1 = fmaf(v.y, w1c[1], a1);
            a2 = fmaf(v.z, w1c[2], a2); a3 = fmaf(v.w, w1c[3], a3);
            v = rp[1];
            a0 = fmaf(v.x, w1c[4], a0); a1 = fmaf(v.y, w1c[5], a1);
            a2 = fmaf(v.z, w1c[6], a2); a3 = fmaf(v.w, w1c[7], a3);
            v = rp[2];
            a0 = fmaf(v.x, w1c[8], a0); a1 = fmaf(v.y, w1c[9], a1);
            a2 = fmaf(v.z, w1c[10], a2); a3 = fmaf(v.w, w1c[11], a3);
#pragma unroll
            for (int t4 = 0; t4 < 5; t4++) {
                v = dp[t4];
                a0 = fmaf(v.x, w1c[12 + 4 * t4 + 0], a0);
                a1 = fmaf(v.y, w1c[12 + 4 * t4 + 1], a1);
                a2 = fmaf(v.z, w1c[12 + 4 * t4 + 2], a2);
                a3 = fmaf(v.w, w1c[12 + 4 * t4 + 3], a3);
            }
            s_h1[p * 68 + lane] = sigmoidf((a0 + a1) + (a2 + a3));
        }
    }
    __syncthreads();

    // ---------------- E: layer2 forward + z3 + gz2 (task p,k,half) ----------
    {
        const int k = lane & 31;
        const int half = lane >> 5;
        float w2c[32];
#pragma unroll
        for (int i = 0; i < 32; i++) w2c[i] = s_W2t[k * 65 + half * 32 + i];
        float w3k = W3[k];
        float b2k = b2[k];
        float b3v = b3[0];
#pragma unroll 1
        for (int p = wid; p < NNBR; p += 4) {
            const float4* hp = (const float4*)(s_h1 + p * 68 + half * 32);
            float a0 = 0.f, a1 = 0.f, a2 = 0.f, a3 = 0.f;
#pragma unroll
            for (int t4 = 0; t4 < 8; t4++) {
                float4 v = hp[t4];
                a0 = fmaf(v.x, w2c[4 * t4 + 0], a0);
                a1 = fmaf(v.y, w2c[4 * t4 + 1], a1);
                a2 = fmaf(v.z, w2c[4 * t4 + 2], a2);
                a3 = fmaf(v.w, w2c[4 * t4 + 3], a3);
            }
            float acc = (a0 + a1) + (a2 + a3);
            acc += __shfl_xor(acc, 32);
            float s = sigmoidf(b2k + acc);
            if (half == 0) s_gz2_red[p * 36 + k] = s_geo[p][0] * w3k * s * (1.f - s);
            float sw = (half == 0) ? s * w3k : 0.f;
            sw += __shfl_xor(sw, 16);
            sw += __shfl_xor(sw, 8);
            sw += __shfl_xor(sw, 4);
            sw += __shfl_xor(sw, 2);
            sw += __shfl_xor(sw, 1);
            if (lane == 0) s_geo[p][5] = b3v + sw;
        }
    }
    __syncthreads();

    // ---------------- G: layer2 backward -> g_z1 in place (task p,h) --------
    {
        float w2r[32];
#pragma unroll
        for (int kk = 0; kk < 32; kk++) w2r[kk] = s_W2t[kk * 65 + lane];
#pragma unroll 1
        for (int p = wid; p < NNBR; p += 4) {
            const float4* gp = (const float4*)(s_gz2_red + p * 36);
            float a0 = 0.f, a1 = 0.f, a2 = 0.f, a3 = 0.f;
#pragma unroll
            for (int t4 = 0; t4 < 8; t4++) {
                float4 v = gp[t4];
                a0 = fmaf(v.x, w2r[4 * t4 + 0], a0);
                a1 = fmaf(v.y, w2r[4 * t4 + 1], a1);
                a2 = fmaf(v.z, w2r[4 * t4 + 2], a2);
                a3 = fmaf(v.w, w2r[4 * t4 + 3], a3);
            }
            float hv = s_h1[p * 68 + lane];
            s_h1[p * 68 + lane] = ((a0 + a1) + (a2 + a3)) * hv * (1.f - hv);
        }
    }
    __syncthreads();

    // ---------------- H: layer1 backward gd[p][d] (task p,d,half) -----------
    {
        const int d = lane & 31;
        const int half = lane >> 5;
        float w1r[32];
#pragma unroll
        for (int i = 0; i < 32; i++) w1r[i] = s_W1[d * 65 + half * 32 + i];
#pragma unroll 1
        for (int p = wid; p < NNBR; p += 4) {
            const float4* gp = (const float4*)(s_h1 + p * 68 + half * 32);
            float a0 = 0.f, a1 = 0.f, a2 = 0.f, a3 = 0.f;
#pragma unroll
            for (int t4 = 0; t4 < 8; t4++) {
                float4 v = gp[t4];
                a0 = fmaf(v.x, w1r[4 * t4 + 0], a0);
                a1 = fmaf(v.y, w1r[4 * t4 + 1], a1);
                a2 = fmaf(v.z, w1r[4 * t4 + 2], a2);
                a3 = fmaf(v.w, w1r[4 * t4 + 3], a3);
            }
            float acc = (a0 + a1) + (a2 + a3);
            acc += __shfl_xor(acc, 32);
            if (half == 0) {
                if (d < NRAD) s_rbf_gdr[p * 16 + d] = acc;
                else          s_d3g[p * 24 + (d - NRAD)] = acc;
            }
        }
    }
    __syncthreads();

    // ------- I: 3-body backward, task (p, chunk of q), shfl-reduced -------
    if (tid < 240) {
        int p = tid >> 3, c = tid & 7;
        int q0 = (c < 6) ? 4 * c : 24 + 3 * (c - 6);
        int qn = (c < 6) ? 4 : 3;
        float Ap[M3];
        {
            const float4* ap4 = (const float4*)(s_d3g + p * 24);
#pragma unroll
            for (int t4 = 0; t4 < 5; t4++) {
                float4 v = ap4[t4];
                Ap[4 * t4 + 0] = v.x; Ap[4 * t4 + 1] = v.y;
                Ap[4 * t4 + 2] = v.z; Ap[4 * t4 + 3] = v.w;
            }
        }
        float fp_ = s_geo[p][0];
        float gu0 = 0.f, gu1 = 0.f, gu2 = 0.f, gfc = 0.f;
        for (int qq = 0; qq < qn; qq++) {
            int q = q0 + qq;
            float cs = s_cos[p * 32 + q];
            float fq = s_geo[q][0];
            const float* Aq = s_d3g + q * 24;
            float E  = __expf(9.5f * cs);
            float Ei = __expf(-9.5f * cs);
            float t9 = cs - MU(9);
            float h9 = __expf(-eta * t9 * t9);
            float sAde = 0.f, sBde = 0.f, sBh = 0.f;
            {
                float h = h9 * E, rr = E * RHO;
#pragma unroll
                for (int m = 10; m < 20; m++) {
                    if (m > 10) { h *= rr; rr *= RHO; }
                    float de = C2 * (cs - MU(m)) * h;
                    float aq = Aq[m];
                    sAde = fmaf(Ap[m], de, sAde);
                    sBde = fmaf(aq, de, sBde);
                    sBh  = fmaf(aq, h,  sBh);
                }
            }
            {
                float h = h9, rr = RHO * Ei;
#pragma unroll
                for (int m = 9; m >= 0; m--) {
                    if (m < 9) { h *= rr; rr *= RHO; }
                    float de = C2 * (cs - MU(m)) * h;
                    float aq = Aq[m];
                    sAde = fmaf(Ap[m], de, sAde);
                    sBde = fmaf(aq, de, sBde);
                    sBh  = fmaf(aq, h,  sBh);
                }
            }
            if (q != p) {
                float gcos = fq * sAde + fp_ * sBde;
                gu0 = fmaf(gcos, s_u[q][0], gu0);
                gu1 = fmaf(gcos, s_u[q][1], gu1);
                gu2 = fmaf(gcos, s_u[q][2], gu2);
                gfc += sBh;
            }
        }
        gu0 += __shfl_xor(gu0, 1); gu0 += __shfl_xor(gu0, 2); gu0 += __shfl_xor(gu0, 4);
        gu1 += __shfl_xor(gu1, 1); gu1 += __shfl_xor(gu1, 2); gu1 += __shfl_xor(gu1, 4);
        gu2 += __shfl_xor(gu2, 1); gu2 += __shfl_xor(gu2, 2); gu2 += __shfl_xor(gu2, 4);
        gfc += __shfl_xor(gfc, 1); gfc += __shfl_xor(gfc, 2); gfc += __shfl_xor(gfc, 4);
        if (c == 0) {
            s_gz2_red[p * 36 + 0] = gu0;
            s_gz2_red[p * 36 + 1] = gu1;
            s_gz2_red[p * 36 + 2] = gu2;
            s_gz2_red[p * 36 + 3] = gfc;
        }
    }
    __syncthreads();

    // ---------------- K: rbf backward + final per-pair + scatter ------------
    float gd0 = 0.f, gd1 = 0.f, gd2 = 0.f, eij = 0.f;
    if (tid < NNBR) {
        float fc = s_geo[tid][0], rinv = s_geo[tid][2];
        float sa = s_geo[tid][3], ca = s_geo[tid][4];
        float out = s_geo[tid][5];
        float u0 = s_u[tid][0], u1 = s_u[tid][1], u2 = s_u[tid][2];
        int j = s_j[tid];
        float grp = 0.f, gfp = 0.f;
        float sprev = 0.f, scur = sa, cprev = 1.f, ccur = ca;
#pragma unroll
        for (int d = 0; d < NRAD; d++) {
            float gdv = s_rbf_gdr[tid * 16 + d];
            float n = (float)(d + 1);
            grp += gdv * fc * sq * rinv * (n * k1 * ccur - scur * rinv);
            gfp += gdv * sq * scur * rinv;
            float snext = 2.f * ca * scur - sprev; sprev = scur; scur = snext;
            float cnext = 2.f * ca * ccur - cprev; cprev = ccur; ccur = cnext;
        }
        float gfc = gfp + s_gz2_red[tid * 36 + 3] + out;
        float gu0 = s_gz2_red[tid * 36 + 0];
        float gu1 = s_gz2_red[tid * 36 + 1];
        float gu2 = s_gz2_red[tid * 36 + 2];
        float grf = grp + gfc * (-0.5f * k1 * sa);
        float gdot = gu0 * u0 + gu1 * u1 + gu2 * u2;
        gd0 = grf * u0 + (gu0 - gdot * u0) * rinv;
        gd1 = grf * u1 + (gu1 - gdot * u1) * rinv;
        gd2 = grf * u2 + (gu2 - gdot * u2) * rinv;
        atomicAdd(&gx[j * 3 + 0], -gd0);
        atomicAdd(&gx[j * 3 + 1], -gd1);
        atomicAdd(&gx[j * 3 + 2], -gd2);
        eij = out * fc;
    }
    if (wid == 0) {
#pragma unroll
        for (int off = 32; off > 0; off >>= 1) {
            gd0 += __shfl_xor(gd0, off);
            gd1 += __shfl_xor(gd1, off);
            gd2 += __shfl_xor(gd2, off);
            eij += __shfl_xor(eij, off);
        }
        if (tid == 0) {
            atomicAdd(&gx[atom * 3 + 0], gd0);
            atomicAdd(&gx[atom * 3 + 1], gd1);
            atomicAdd(&gx[atom * 3 + 2], gd2);
            e_atom[atom] = eij;
        }
    }
}

// blocks 0..7: per-config energy reduction; blocks 8..: forces = -gx
extern "C" __global__ void __launch_bounds__(256)
fit_finalize(const float* __restrict__ e_atom, const float* __restrict__ gx,
             float* __restrict__ out)
{
    int b = blockIdx.x;
    if (b < NCONF) {
        __shared__ float red[256];
        int t = threadIdx.x;
        red[t] = (t < APC) ? e_atom[b * APC + t] : 0.f;
        __syncthreads();
        for (int s = 128; s > 0; s >>= 1) {
            if (t < s) red[t] += red[t + s];
            __syncthreads();
        }
        if (t == 0) out[b] = red[0];
    } else {
        int idx = (b - NCONF) * 256 + threadIdx.x;
        if (idx < NATOMS * 3) out[NCONF + idx] = -gx[idx];
    }
}

extern "C" void kernel_launch(void* const* d_in, const int* in_sizes, int n_in,
                              void* d_out, int out_size, void* d_ws, size_t ws_size,
                              hipStream_t stream)
{
    const float* x  = (const float*)d_in[0];
    const float* tx = (const float*)d_in[1];
    const int*   uj = (const int*)d_in[7];
    const float* W1 = (const float*)d_in[8];
    const float* b1 = (const float*)d_in[9];
    const float* W2 = (const float*)d_in[10];
    const float* b2 = (const float*)d_in[11];
    const float* W3 = (const float*)d_in[12];
    const float* b3 = (const float*)d_in[13];

    float* gx     = (float*)d_ws;           // [NATOMS*3]
    float* e_atom = gx + NATOMS * 3;        // [NATOMS]

    hipMemsetAsync(gx, 0, NATOMS * 3 * sizeof(float), stream);

    fit_main<<<NATOMS, 256, 0, stream>>>(x, tx, uj, W1, b1, W2, b2, W3, b3,
                                         gx, e_atom);

    int fblocks = NCONF + (NATOMS * 3 + 255) / 256;   // 8 + 24
    fit_finalize<<<fblocks, 256, 0, stream>>>(e_atom, gx, (float*)d_out);
}

// Round 9
// 46.445 us; speedup vs baseline: 9.3602x; 1.4408x over previous
//
#include <hip/hip_runtime.h>
#include <math.h>

#define NATOMS 2000
#define NNBR   30
#define NCONF  8
#define APC    250
#define NRAD   12
#define M3     20
#define H1N    64
#define H2N    32

#define MU(m) (-1.0f + (float)(m) * (2.0f / 19.0f))

typedef __attribute__((ext_vector_type(8))) short short8_t;   // bf16x8 MFMA frag
typedef __attribute__((ext_vector_type(4))) float f32x4;

__device__ __forceinline__ float sigmoidf(float v) {
    return 1.0f / (1.0f + __expf(-v));
}
__device__ __forceinline__ ushort f2bf(float f) {
    unsigned u = __float_as_uint(f);
    u += 0x7FFF + ((u >> 16) & 1);          // RNE
    return (ushort)(u >> 16);
}
__device__ __forceinline__ float bf2f(ushort s) {
    return __uint_as_float(((unsigned)s) << 16);
}

// One atom per 256-thread block.
// MLP fwd+bwd = 4 per-block bf16 MFMA GEMMs (16x16x32), 4 waves = 4 (M,N) tiles.
// 3-body fwd/bwd: task-(p,qchunk) scalar phases with 3-exp Gaussian recurrence.
extern "C" __global__ void __launch_bounds__(256)
fit_main(const float* __restrict__ x, const float* __restrict__ tx,
         const int* __restrict__ uj,
         const float* __restrict__ W1, const float* __restrict__ b1,
         const float* __restrict__ W2, const float* __restrict__ b2,
         const float* __restrict__ W3, const float* __restrict__ b3,
         float* __restrict__ gx, float* __restrict__ e_atom)
{
    const int tid  = threadIdx.x;
    const int lane = tid & 63;
    const int wid  = tid >> 6;
    const int atom = blockIdx.x;
    const int lr   = lane & 15;     // MFMA row/col index
    const int lg   = lane >> 4;     // MFMA k-group / reg-group

    __shared__ float  s_u[NNBR][4];
    __shared__ float  s_geo[NNBR][8];     // 0:fc 1:r 2:rinv 3:sa 4:ca
    __shared__ int    s_j[NNBR];
    __shared__ __align__(16) float  s_desc[32 * 36];   // [p][d], rows 30/31 zero
    __shared__ __align__(16) ushort s_W1b[32 * 72];    // bf16 W1 [d][h]
    __shared__ __align__(16) ushort s_W2tb[32 * 72];   // bf16 W2t [k2][h]
    __shared__ __align__(16) ushort s_h1b[32 * 72];    // bf16 h1, later g_z1
    __shared__ __align__(16) ushort s_gz2b[32 * 40];   // bf16 gz2
    __shared__ __align__(16) float  s_gd[32 * 44];     // fp32 gd [p][d]
    __shared__ float  s_outp[64];                      // z3 partials [nt][p]
    __shared__ float  s_red[32 * 5];                   // gu0..2, gfc per p

    const float k1  = 0.6283185307179586f;   // pi/5
    const float sq  = 0.6324555320336759f;   // sqrt(2/5)
    const float eta = 45.125f;               // 1/(2*dmu^2)
    const float RHO = 0.36787944117144233f;  // exp(-1)
    const float C2  = -90.25f;               // -2*eta

    // ---------------- A: stage bf16 weights + pair geometry ----------------
#pragma unroll
    for (int i = 0; i < 8; i++) {
        int idx = tid + 256 * i;               // W1 [32][64]
        s_W1b[(idx >> 6) * 72 + (idx & 63)] = f2bf(W1[idx]);
    }
#pragma unroll
    for (int i = 0; i < 8; i++) {
        int idx = tid + 256 * i;               // W2 [64][32] -> [k2][h]
        s_W2tb[(idx & 31) * 72 + (idx >> 5)] = f2bf(W2[idx]);
    }
    if (tid < NNBR) {
        int p = atom * NNBR + tid;
        int j = uj[p];
        float d0 = x[atom * 3 + 0] - x[j * 3 + 0] - tx[p * 3 + 0];
        float d1 = x[atom * 3 + 1] - x[j * 3 + 1] - tx[p * 3 + 1];
        float d2 = x[atom * 3 + 2] - x[j * 3 + 2] - tx[p * 3 + 2];
        float r = sqrtf(d0 * d0 + d1 * d1 + d2 * d2);
        float rinv = 1.0f / r;
        float sa, ca;
        __sincosf(k1 * r, &sa, &ca);
        float fc = 0.5f * (ca + 1.0f);
        s_u[tid][0] = d0 * rinv; s_u[tid][1] = d1 * rinv; s_u[tid][2] = d2 * rinv;
        s_geo[tid][0] = fc; s_geo[tid][1] = r; s_geo[tid][2] = rinv;
        s_geo[tid][3] = sa; s_geo[tid][4] = ca;
        s_j[tid] = j;
    }
    __syncthreads();

    // ------- B+C: rbf, zero pad rows, 3-body forward into s_desc -------
#pragma unroll 1
    for (int t = tid; t < NNBR * NRAD; t += 256) {
        int p = t / NRAD, n = t - p * NRAD;
        float s = __sinf((float)(n + 1) * k1 * s_geo[p][1]);
        s_desc[p * 36 + n] = s_geo[p][0] * sq * s * s_geo[p][2];
    }
    if (tid < 72) s_desc[30 * 36 + tid] = 0.f;     // pad rows 30,31 (cols 0..35)
    if (tid < 240) {
        int p = tid >> 3, c = tid & 7;
        int q0 = (c < 6) ? 4 * c : 24 + 3 * (c - 6);
        int qn = (c < 6) ? 4 : 3;
        float up0 = s_u[p][0], up1 = s_u[p][1], up2 = s_u[p][2];
        float d3part[M3];
#pragma unroll
        for (int m = 0; m < M3; m++) d3part[m] = 0.f;
        for (int qq = 0; qq < qn; qq++) {
            int q = q0 + qq;
            float fq = (q == p) ? 0.f : s_geo[q][0];
            float cs = up0 * s_u[q][0] + up1 * s_u[q][1] + up2 * s_u[q][2];
            float E  = __expf(9.5f * cs);
            float Ei = __expf(-9.5f * cs);
            float t9 = cs - MU(9);
            float h9 = __expf(-eta * t9 * t9);
            float h = h9 * E, rr = E * RHO;
            d3part[10] = fmaf(fq, h, d3part[10]);
#pragma unroll
            for (int m = 11; m < 20; m++) {
                h *= rr; rr *= RHO;
                d3part[m] = fmaf(fq, h, d3part[m]);
            }
            h = h9; rr = RHO * Ei;
            d3part[9] = fmaf(fq, h, d3part[9]);
#pragma unroll
            for (int m = 8; m >= 0; m--) {
                h *= rr; rr *= RHO;
                d3part[m] = fmaf(fq, h, d3part[m]);
            }
        }
#pragma unroll
        for (int m = 0; m < M3; m++) {
            float v = d3part[m];
            v += __shfl_xor(v, 1);
            v += __shfl_xor(v, 2);
            v += __shfl_xor(v, 4);
            if (c == 0) s_desc[p * 36 + NRAD + m] = v;
        }
    }
    __syncthreads();

    // ---- GEMM1: z1[32][64] = desc @ W1; h1 = sigmoid(z1+b1) -> s_h1b ----
    {
        const int mt = wid & 1, ntb = (wid >> 1) * 2;
        short8_t a;
        {
            const float* dp = s_desc + (16 * mt + lr) * 36 + lg * 8;
            f32x4 v0 = *(const f32x4*)dp;
            f32x4 v1 = *(const f32x4*)(dp + 4);
            a[0] = (short)f2bf(v0[0]); a[1] = (short)f2bf(v0[1]);
            a[2] = (short)f2bf(v0[2]); a[3] = (short)f2bf(v0[3]);
            a[4] = (short)f2bf(v1[0]); a[5] = (short)f2bf(v1[1]);
            a[6] = (short)f2bf(v1[2]); a[7] = (short)f2bf(v1[3]);
        }
#pragma unroll
        for (int t = 0; t < 2; t++) {
            int nt = ntb + t;
            int col = 16 * nt + lr;
            short8_t b;
#pragma unroll
            for (int j = 0; j < 8; j++)
                b[j] = (short)s_W1b[(lg * 8 + j) * 72 + col];
            f32x4 c = {0.f, 0.f, 0.f, 0.f};
            c = __builtin_amdgcn_mfma_f32_16x16x32_bf16(a, b, c, 0, 0, 0);
            float b1v = b1[col];
#pragma unroll
            for (int rg = 0; rg < 4; rg++) {
                int p = 16 * mt + lg * 4 + rg;
                s_h1b[p * 72 + col] = f2bf(sigmoidf(c[rg] + b1v));
            }
        }
    }
    __syncthreads();

    // ---- GEMM2: z2[32][32] = h1 @ W2; s2, gz2 -> s_gz2b; z3 partials ----
    {
        const int mt = wid & 1, nt = wid >> 1;
        f32x4 c = {0.f, 0.f, 0.f, 0.f};
#pragma unroll
        for (int kt = 0; kt < 2; kt++) {
            short8_t a = *(const short8_t*)&s_h1b[(16 * mt + lr) * 72 + kt * 32 + lg * 8];
            short8_t b = *(const short8_t*)&s_W2tb[(16 * nt + lr) * 72 + kt * 32 + lg * 8];
            c = __builtin_amdgcn_mfma_f32_16x16x32_bf16(a, b, c, 0, 0, 0);
        }
        int k2 = 16 * nt + lr;
        float b2v = b2[k2], w3v = W3[k2];
        float op[4];
#pragma unroll
        for (int rg = 0; rg < 4; rg++) {
            int p = 16 * mt + lg * 4 + rg;
            float s = sigmoidf(c[rg] + b2v);
            op[rg] = s * w3v;
            float g = (p < NNBR) ? s_geo[p][0] * w3v * s * (1.f - s) : 0.f;
            s_gz2b[p * 40 + k2] = f2bf(g);
        }
#pragma unroll
        for (int rg = 0; rg < 4; rg++) {
            op[rg] += __shfl_xor(op[rg], 1);
            op[rg] += __shfl_xor(op[rg], 2);
            op[rg] += __shfl_xor(op[rg], 4);
            op[rg] += __shfl_xor(op[rg], 8);
        }
        if (lr == 0) {
#pragma unroll
            for (int rg = 0; rg < 4; rg++)
                s_outp[nt * 32 + 16 * mt + lg * 4 + rg] = op[rg];
        }
    }
    __syncthreads();

    // ---- GEMM3: gh1[32][64] = gz2 @ W2^T; gz1 = gh1*h1*(1-h1) in-place ----
    {
        const int mt = wid & 1, ntb = (wid >> 1) * 2;
        short8_t a = *(const short8_t*)&s_gz2b[(16 * mt + lr) * 40 + lg * 8];
#pragma unroll
        for (int t = 0; t < 2; t++) {
            int nt = ntb + t;
            int hcol = 16 * nt + lr;
            short8_t b;
#pragma unroll
            for (int j = 0; j < 8; j++)
                b[j] = (short)s_W2tb[(lg * 8 + j) * 72 + hcol];
            f32x4 c = {0.f, 0.f, 0.f, 0.f};
            c = __builtin_amdgcn_mfma_f32_16x16x32_bf16(a, b, c, 0, 0, 0);
#pragma unroll
            for (int rg = 0; rg < 4; rg++) {
                int p = 16 * mt + lg * 4 + rg;
                float hv = bf2f(s_h1b[p * 72 + hcol]);
                s_h1b[p * 72 + hcol] = f2bf(c[rg] * hv * (1.f - hv));
            }
        }
    }
    __syncthreads();

    // ---- GEMM4: gd[32][32] = gz1 @ W1^T -> s_gd (fp32) ----
    {
        const int mt = wid & 1, nt = wid >> 1;
        f32x4 c = {0.f, 0.f, 0.f, 0.f};
#pragma unroll
        for (int kt = 0; kt < 2; kt++) {
            short8_t a = *(const short8_t*)&s_h1b[(16 * mt + lr) * 72 + kt * 32 + lg * 8];
            short8_t b = *(const short8_t*)&s_W1b[(16 * nt + lr) * 72 + kt * 32 + lg * 8];
            c = __builtin_amdgcn_mfma_f32_16x16x32_bf16(a, b, c, 0, 0, 0);
        }
        int d = 16 * nt + lr;
#pragma unroll
        for (int rg = 0; rg < 4; rg++)
            s_gd[(16 * mt + lg * 4 + rg) * 44 + d] = c[rg];
    }
    __syncthreads();

    // ------- I: 3-body backward, task (p, q-chunk), shfl-reduced -------
    if (tid < 240) {
        int p = tid >> 3, c = tid & 7;
        int q0 = (c < 6) ? 4 * c : 24 + 3 * (c - 6);
        int qn = (c < 6) ? 4 : 3;
        float up0 = s_u[p][0], up1 = s_u[p][1], up2 = s_u[p][2];
        float Ap[M3];
        {
            const f32x4* ap4 = (const f32x4*)(s_gd + p * 44 + NRAD);
#pragma unroll
            for (int t4 = 0; t4 < 5; t4++) {
                f32x4 v = ap4[t4];
                Ap[4 * t4 + 0] = v[0]; Ap[4 * t4 + 1] = v[1];
                Ap[4 * t4 + 2] = v[2]; Ap[4 * t4 + 3] = v[3];
            }
        }
        float fp_ = s_geo[p][0];
        float gu0 = 0.f, gu1 = 0.f, gu2 = 0.f, gfc = 0.f;
        for (int qq = 0; qq < qn; qq++) {
            int q = q0 + qq;
            float uq0 = s_u[q][0], uq1 = s_u[q][1], uq2 = s_u[q][2];
            float cs = up0 * uq0 + up1 * uq1 + up2 * uq2;
            float fq = s_geo[q][0];
            const float* Aq = s_gd + q * 44 + NRAD;
            float E  = __expf(9.5f * cs);
            float Ei = __expf(-9.5f * cs);
            float t9 = cs - MU(9);
            float h9 = __expf(-eta * t9 * t9);
            float sAde = 0.f, sBde = 0.f, sBh = 0.f;
            {
                float h = h9 * E, rr = E * RHO;
#pragma unroll
                for (int m = 10; m < 20; m++) {
                    if (m > 10) { h *= rr; rr *= RHO; }
                    float de = C2 * (cs - MU(m)) * h;
                    float aq = Aq[m];
                    sAde = fmaf(Ap[m], de, sAde);
                    sBde = fmaf(aq, de, sBde);
                    sBh  = fmaf(aq, h,  sBh);
                }
            }
            {
                float h = h9, rr = RHO * Ei;
#pragma unroll
                for (int m = 9; m >= 0; m--) {
                    if (m < 9) { h *= rr; rr *= RHO; }
                    float de = C2 * (cs - MU(m)) * h;
                    float aq = Aq[m];
                    sAde = fmaf(Ap[m], de, sAde);
                    sBde = fmaf(aq, de, sBde);
                    sBh  = fmaf(aq, h,  sBh);
                }
            }
            if (q != p) {
                float gcos = fq * sAde + fp_ * sBde;
                gu0 = fmaf(gcos, uq0, gu0);
                gu1 = fmaf(gcos, uq1, gu1);
                gu2 = fmaf(gcos, uq2, gu2);
                gfc += sBh;
            }
        }
        gu0 += __shfl_xor(gu0, 1); gu0 += __shfl_xor(gu0, 2); gu0 += __shfl_xor(gu0, 4);
        gu1 += __shfl_xor(gu1, 1); gu1 += __shfl_xor(gu1, 2); gu1 += __shfl_xor(gu1, 4);
        gu2 += __shfl_xor(gu2, 1); gu2 += __shfl_xor(gu2, 2); gu2 += __shfl_xor(gu2, 4);
        gfc += __shfl_xor(gfc, 1); gfc += __shfl_xor(gfc, 2); gfc += __shfl_xor(gfc, 4);
        if (c == 0) {
            s_red[p * 5 + 0] = gu0;
            s_red[p * 5 + 1] = gu1;
            s_red[p * 5 + 2] = gu2;
            s_red[p * 5 + 3] = gfc;
        }
    }
    __syncthreads();

    // ---------------- K: rbf backward + final per-pair + scatter ------------
    float gd0 = 0.f, gd1 = 0.f, gd2 = 0.f, eij = 0.f;
    if (tid < NNBR) {
        float fc = s_geo[tid][0], rinv = s_geo[tid][2];
        float sa = s_geo[tid][3], ca = s_geo[tid][4];
        float out = b3[0] + s_outp[tid] + s_outp[32 + tid];
        float u0 = s_u[tid][0], u1 = s_u[tid][1], u2 = s_u[tid][2];
        int j = s_j[tid];
        float grp = 0.f, gfp = 0.f;
        float sprev = 0.f, scur = sa, cprev = 1.f, ccur = ca;
#pragma unroll
        for (int d = 0; d < NRAD; d++) {
            float gdv = s_gd[tid * 44 + d];
            float n = (float)(d + 1);
            grp += gdv * fc * sq * rinv * (n * k1 * ccur - scur * rinv);
            gfp += gdv * sq * scur * rinv;
            float snext = 2.f * ca * scur - sprev; sprev = scur; scur = snext;
            float cnext = 2.f * ca * ccur - cprev; cprev = ccur; ccur = cnext;
        }
        float gfc = gfp + s_red[tid * 5 + 3] + out;
        float gu0 = s_red[tid * 5 + 0];
        float gu1 = s_red[tid * 5 + 1];
        float gu2 = s_red[tid * 5 + 2];
        float grf = grp + gfc * (-0.5f * k1 * sa);
        float gdot = gu0 * u0 + gu1 * u1 + gu2 * u2;
        gd0 = grf * u0 + (gu0 - gdot * u0) * rinv;
        gd1 = grf * u1 + (gu1 - gdot * u1) * rinv;
        gd2 = grf * u2 + (gu2 - gdot * u2) * rinv;
        atomicAdd(&gx[j * 3 + 0], -gd0);
        atomicAdd(&gx[j * 3 + 1], -gd1);
        atomicAdd(&gx[j * 3 + 2], -gd2);
        eij = out * fc;
    }
    if (wid == 0) {
#pragma unroll
        for (int off = 32; off > 0; off >>= 1) {
            gd0 += __shfl_xor(gd0, off);
            gd1 += __shfl_xor(gd1, off);
            gd2 += __shfl_xor(gd2, off);
            eij += __shfl_xor(eij, off);
        }
        if (tid == 0) {
            atomicAdd(&gx[atom * 3 + 0], gd0);
            atomicAdd(&gx[atom * 3 + 1], gd1);
            atomicAdd(&gx[atom * 3 + 2], gd2);
            e_atom[atom] = eij;
        }
    }
}

// blocks 0..7: per-config energy reduction; blocks 8..: forces = -gx
extern "C" __global__ void __launch_bounds__(256)
fit_finalize(const float* __restrict__ e_atom, const float* __restrict__ gx,
             float* __restrict__ out)
{
    int b = blockIdx.x;
    if (b < NCONF) {
        __shared__ float red[256];
        int t = threadIdx.x;
        red[t] = (t < APC) ? e_atom[b * APC + t] : 0.f;
        __syncthreads();
        for (int s = 128; s > 0; s >>= 1) {
            if (t < s) red[t] += red[t + s];
            __syncthreads();
        }
        if (t == 0) out[b] = red[0];
    } else {
        int idx = (b - NCONF) * 256 + threadIdx.x;
        if (idx < NATOMS * 3) out[NCONF + idx] = -gx[idx];
    }
}

extern "C" void kernel_launch(void* const* d_in, const int* in_sizes, int n_in,
                              void* d_out, int out_size, void* d_ws, size_t ws_size,
                              hipStream_t stream)
{
    const float* x  = (const float*)d_in[0];
    const float* tx = (const float*)d_in[1];
    const int*   uj = (const int*)d_in[7];
    const float* W1 = (const float*)d_in[8];
    const float* b1 = (const float*)d_in[9];
    const float* W2 = (const float*)d_in[10];
    const float* b2 = (const float*)d_in[11];
    const float* W3 = (const float*)d_in[12];
    const float* b3 = (const float*)d_in[13];

    float* gx     = (float*)d_ws;           // [NATOMS*3]
    float* e_atom = gx + NATOMS * 3;        // [NATOMS]

    hipMemsetAsync(gx, 0, NATOMS * 3 * sizeof(float), stream);

    fit_main<<<NATOMS, 256, 0, stream>>>(x, tx, uj, W1, b1, W2, b2, W3, b3,
                                         gx, e_atom);

    int fblocks = NCONF + (NATOMS * 3 + 255) / 256;   // 8 + 24
    fit_finalize<<<fblocks, 256, 0, stream>>>(e_atom, gx, (float*)d_out);
}